// Round 1
// baseline (791.897 us; speedup 1.0000x reference)
//
#include <hip/hip_runtime.h>

#define N_NODES 50000
#define N_EDGES 800000
#define E_TOT   850000   // N_EDGES + N_NODES self loops
#define HC 128
#define NEG_SLOPE 0.2f

// ---------------- helpers ----------------
__device__ __forceinline__ int edge_get(const void* eidx, int f64, long long i) {
  return f64 ? (int)((const long long*)eidx)[i] : ((const int*)eidx)[i];
}
// online softmax accumulate: state (m, s) <- value a
__device__ __forceinline__ void ms_upd(float& m, float& s, float a) {
  float mn = fmaxf(m, a);
  s = s * expf(m - mn) + expf(a - mn);   // m=-inf -> expf(-inf)=0, safe
  m = mn;
}
// combine two (m,s) states; safe when either/both are (-inf, 0)
__device__ __forceinline__ void ms_comb(float& m, float& s, float m2, float s2) {
  float mn = fmaxf(m, m2);
  float sa = (m == mn)  ? s  : s  * expf(m  - mn);
  float sb = (m2 == mn) ? s2 : s2 * expf(m2 - mn);
  m = mn; s = sa + sb;
}

// ---------------- setup kernels ----------------
// probe whether edge_index buffer is int64 (all values in [0,N)) or int32
__global__ void detect_kernel(const void* eidx, int* flag) {
  if (threadIdx.x == 0 && blockIdx.x == 0) {
    const long long* p = (const long long*)eidx;
    int ok = 1;
    for (int i = 0; i < 64; ++i) {
      long long v = p[i];
      if (v < 0 || v >= N_NODES) { ok = 0; break; }
    }
    *flag = ok;
  }
}

__global__ __launch_bounds__(256) void reduce_sum_kernel(const float* __restrict__ w,
                                                         float* __restrict__ scal, int e) {
  __shared__ float sh[4];
  float s = 0.f;
  for (int i = blockIdx.x * blockDim.x + threadIdx.x; i < e; i += gridDim.x * blockDim.x)
    s += w[i];
  #pragma unroll
  for (int m = 32; m >= 1; m >>= 1) s += __shfl_xor(s, m, 64);
  int lane = threadIdx.x & 63, wv = threadIdx.x >> 6;
  if (lane == 0) sh[wv] = s;
  __syncthreads();
  if (threadIdx.x == 0) {
    float t = sh[0] + sh[1] + sh[2] + sh[3];
    atomicAdd(&scal[0], t);
  }
}

// scal layout (floats): [0]=sum(ew) [1]=mean [4..7]=c1 [8..11]=c2 ; ((int*)scal)[16]=int64-flag
__global__ void prep_c_kernel(const float* __restrict__ We1, const float* __restrict__ ae1,
                              const float* __restrict__ We2, const float* __restrict__ ae2,
                              float* __restrict__ scal, float inv_e) {
  int t = threadIdx.x;
  float p = (t < 128) ? We1[t] * ae1[t] : We2[t - 128] * ae2[t - 128];
  #pragma unroll
  for (int m = 16; m >= 1; m >>= 1) p += __shfl_xor(p, m, 32);
  if ((t & 31) == 0) {
    int hd = (t & 127) >> 5;
    if (t < 128) scal[4 + hd] = p; else scal[8 + hd] = p;
  }
  if (t == 0) scal[1] = scal[0] * inv_e;
}

__global__ void hist_kernel(const void* eidx, const int* __restrict__ flag,
                            int* __restrict__ counts) {
  int pidx = blockIdx.x * 256 + threadIdx.x;
  if (pidx >= E_TOT) return;
  int f = *flag;
  int d = (pidx < N_EDGES) ? edge_get(eidx, f, (long long)N_EDGES + pidx)
                           : (pidx - N_EDGES);
  atomicAdd(&counts[d], 1);
}

// single-block exclusive scan, 8 elements/thread
__global__ __launch_bounds__(1024) void scan_kernel(const int* __restrict__ counts,
    int* __restrict__ offs, int* __restrict__ cursor, int n, int total) {
  __shared__ int buf[1024];
  int carry = 0;
  const int CHUNK = 8192;
  for (int base = 0; base < n; base += CHUNK) {
    int i0 = base + (int)threadIdx.x * 8;
    int v[8]; int local = 0;
    #pragma unroll
    for (int j = 0; j < 8; ++j) {
      int idx = i0 + j;
      v[j] = (idx < n) ? counts[idx] : 0;
      local += v[j];
    }
    buf[threadIdx.x] = local;
    __syncthreads();
    for (int off = 1; off < 1024; off <<= 1) {
      int t = ((int)threadIdx.x >= off) ? buf[threadIdx.x - off] : 0;
      __syncthreads();
      buf[threadIdx.x] += t;
      __syncthreads();
    }
    int run = carry + buf[threadIdx.x] - local;
    carry += buf[1023];
    #pragma unroll
    for (int j = 0; j < 8; ++j) {
      int idx = i0 + j;
      if (idx < n) { offs[idx] = run; cursor[idx] = run; }
      run += v[j];
    }
    __syncthreads();
  }
  if (threadIdx.x == 0) offs[n] = total;
}

__global__ void scatter_kernel(const void* eidx, const int* __restrict__ flag,
    const float* __restrict__ ew, const float* __restrict__ scal,
    int* __restrict__ cursor, int* __restrict__ esrc, int* __restrict__ edst,
    float* __restrict__ ewc) {
  int pidx = blockIdx.x * 256 + threadIdx.x;
  if (pidx >= E_TOT) return;
  int f = *flag;
  int s, d; float w;
  if (pidx < N_EDGES) {
    s = edge_get(eidx, f, pidx);
    d = edge_get(eidx, f, (long long)N_EDGES + pidx);
    w = ew[pidx];
  } else {
    s = d = pidx - N_EDGES;
    w = scal[1];
  }
  int pos = atomicAdd(&cursor[d], 1);
  esrc[pos] = s; edst[pos] = d; ewc[pos] = w;
}

// ---------------- GEMM: C[M x 128] = A[M x K] * B[K x 128], fp32 ----------------
#define GBM 64
#define GBN 128
#define GBK 16
__global__ __launch_bounds__(256) void sgemm_kernel(const float* __restrict__ A,
    const float* __restrict__ B, float* __restrict__ C, int M, int K) {
  __shared__ float As[GBK][GBM + 4];   // stored transposed [k][m], +4 pad keeps 16B align
  __shared__ float Bs[GBK][GBN];
  int tid  = threadIdx.x;
  int bm   = blockIdx.x * GBM;
  int la_r = tid >> 2;            // 0..63
  int la_k = (tid & 3) << 2;      // 0,4,8,12
  int lb_r = tid >> 5;            // 0..7
  int lb_c = (tid & 31) << 2;     // 0..124
  int trow = tid >> 5;            // 0..7  -> rows trow*8..+7
  int tcol = tid & 31;            // 0..31 -> cols tcol*4..+3
  float acc[8][4];
  #pragma unroll
  for (int i = 0; i < 8; ++i)
    #pragma unroll
    for (int j = 0; j < 4; ++j) acc[i][j] = 0.f;

  for (int k0 = 0; k0 < K; k0 += GBK) {
    int gr = bm + la_r;
    float4 av = make_float4(0.f, 0.f, 0.f, 0.f);
    if (gr < M) av = *(const float4*)(A + (size_t)gr * K + k0 + la_k);
    float4 bv0 = *(const float4*)(B + (size_t)(k0 + lb_r) * GBN + lb_c);
    float4 bv1 = *(const float4*)(B + (size_t)(k0 + lb_r + 8) * GBN + lb_c);
    __syncthreads();
    As[la_k + 0][la_r] = av.x; As[la_k + 1][la_r] = av.y;
    As[la_k + 2][la_r] = av.z; As[la_k + 3][la_r] = av.w;
    *(float4*)&Bs[lb_r][lb_c]     = bv0;
    *(float4*)&Bs[lb_r + 8][lb_c] = bv1;
    __syncthreads();
    #pragma unroll
    for (int kk = 0; kk < GBK; ++kk) {
      float4 a0 = *(const float4*)&As[kk][trow * 8];
      float4 a1 = *(const float4*)&As[kk][trow * 8 + 4];
      float4 b  = *(const float4*)&Bs[kk][tcol * 4];
      float av8[8] = {a0.x, a0.y, a0.z, a0.w, a1.x, a1.y, a1.z, a1.w};
      #pragma unroll
      for (int i = 0; i < 8; ++i) {
        acc[i][0] += av8[i] * b.x;
        acc[i][1] += av8[i] * b.y;
        acc[i][2] += av8[i] * b.z;
        acc[i][3] += av8[i] * b.w;
      }
    }
  }
  #pragma unroll
  for (int i = 0; i < 8; ++i) {
    int r = bm + trow * 8 + i;
    if (r < M)
      *(float4*)(C + (size_t)r * GBN + tcol * 4) =
          make_float4(acc[i][0], acc[i][1], acc[i][2], acc[i][3]);
  }
}

// ---------------- per-node attention coefficients ----------------
__global__ __launch_bounds__(256) void attn_coef_kernel(const float* __restrict__ h,
    const float* __restrict__ att_s, const float* __restrict__ att_d,
    float* __restrict__ a_s, float* __restrict__ a_d, int n) {
  int node = blockIdx.x * 2 + ((int)threadIdx.x >> 7);
  int d = threadIdx.x & 127;
  if (node >= n) return;
  float v  = h[(size_t)node * HC + d];
  float ps = v * att_s[d];
  float pd = v * att_d[d];
  #pragma unroll
  for (int m = 16; m >= 1; m >>= 1) {
    ps += __shfl_xor(ps, m, 32);
    pd += __shfl_xor(pd, m, 32);
  }
  if ((d & 31) == 0) {
    a_s[node * 4 + (d >> 5)] = ps;
    a_d[node * 4 + (d >> 5)] = pd;
  }
}

// ---------------- per-edge alpha (CSR order) ----------------
__global__ __launch_bounds__(256) void alpha_kernel(const float* __restrict__ a_s,
    const float* __restrict__ a_d, const int* __restrict__ esrc,
    const int* __restrict__ edst, const float* __restrict__ ewc,
    const float* __restrict__ cptr, float4* __restrict__ alpha) {
  int pidx = blockIdx.x * 256 + threadIdx.x;
  if (pidx >= E_TOT) return;
  float4 c = *(const float4*)cptr;
  int s = esrc[pidx], d = edst[pidx];
  float w = ewc[pidx];
  float4 as = *(const float4*)(a_s + (size_t)s * 4);
  float4 ad = *(const float4*)(a_d + (size_t)d * 4);
  float4 r;
  r.x = as.x + ad.x + w * c.x; r.x = r.x > 0.f ? r.x : NEG_SLOPE * r.x;
  r.y = as.y + ad.y + w * c.y; r.y = r.y > 0.f ? r.y : NEG_SLOPE * r.y;
  r.z = as.z + ad.z + w * c.z; r.z = r.z > 0.f ? r.z : NEG_SLOPE * r.z;
  r.w = as.w + ad.w + w * c.w; r.w = r.w > 0.f ? r.w : NEG_SLOPE * r.w;
  alpha[pidx] = r;
}

// ---------------- softmax + aggregation, one block (128 thr) per node ----------------
#define AGG_TILE 512
__global__ __launch_bounds__(128) void aggregate_kernel(const float* __restrict__ h,
    const float4* __restrict__ alpha, const int* __restrict__ offs,
    const int* __restrict__ esrc, const float* __restrict__ bias,
    float* __restrict__ out, int n) {
  __shared__ float4 wbuf[AGG_TILE];
  __shared__ int   sbuf[AGG_TILE];
  __shared__ float red[2][8];
  int v   = blockIdx.x;
  int tid = threadIdx.x;
  int r0  = offs[v];
  int deg = offs[v + 1] - r0;

  float m[4] = {-INFINITY, -INFINITY, -INFINITY, -INFINITY};
  float s[4] = {0.f, 0.f, 0.f, 0.f};
  for (int i = tid; i < deg; i += 128) {
    float4 a = alpha[r0 + i];
    ms_upd(m[0], s[0], a.x);
    ms_upd(m[1], s[1], a.y);
    ms_upd(m[2], s[2], a.z);
    ms_upd(m[3], s[3], a.w);
  }
  #pragma unroll
  for (int off = 1; off < 64; off <<= 1) {
    #pragma unroll
    for (int hd = 0; hd < 4; ++hd) {
      float m2 = __shfl_xor(m[hd], off, 64);
      float s2 = __shfl_xor(s[hd], off, 64);
      ms_comb(m[hd], s[hd], m2, s2);
    }
  }
  int wv = tid >> 6;
  if ((tid & 63) == 0) {
    #pragma unroll
    for (int hd = 0; hd < 4; ++hd) { red[wv][hd] = m[hd]; red[wv][4 + hd] = s[hd]; }
  }
  __syncthreads();
  float M4[4], inv[4];
  #pragma unroll
  for (int hd = 0; hd < 4; ++hd) {
    float m0 = red[0][hd], s0 = red[0][4 + hd];
    float m1 = red[1][hd], s1 = red[1][4 + hd];
    ms_comb(m0, s0, m1, s1);
    M4[hd] = m0;
    inv[hd] = 1.0f / s0;
  }
  int head = tid >> 5;
  float acc = 0.f;
  for (int base = 0; base < deg; base += AGG_TILE) {
    int tile = min(AGG_TILE, deg - base);
    __syncthreads();
    for (int i = tid; i < tile; i += 128) {
      float4 a = alpha[r0 + base + i];
      wbuf[i] = make_float4(expf(a.x - M4[0]) * inv[0],
                            expf(a.y - M4[1]) * inv[1],
                            expf(a.z - M4[2]) * inv[2],
                            expf(a.w - M4[3]) * inv[3]);
      sbuf[i] = esrc[r0 + base + i];
    }
    __syncthreads();
    #pragma unroll 2
    for (int i = 0; i < tile; ++i) {
      float w = ((const float*)&wbuf[i])[head];
      acc += w * h[(size_t)sbuf[i] * HC + tid];
    }
  }
  out[(size_t)v * HC + tid] = acc + bias[tid];
}

// ---------------- launcher ----------------
extern "C" void kernel_launch(void* const* d_in, const int* in_sizes, int n_in,
                              void* d_out, int out_size, void* d_ws, size_t ws_size,
                              hipStream_t stream) {
  const float* x   = (const float*)d_in[0];
  const void*  ei  = d_in[1];
  const float* ew  = (const float*)d_in[2];
  const float* W1  = (const float*)d_in[3];
  const float* as1 = (const float*)d_in[4];
  const float* ad1 = (const float*)d_in[5];
  const float* We1 = (const float*)d_in[6];
  const float* ae1 = (const float*)d_in[7];
  const float* b1  = (const float*)d_in[8];
  const float* W2  = (const float*)d_in[9];
  const float* as2 = (const float*)d_in[10];
  const float* ad2 = (const float*)d_in[11];
  const float* We2 = (const float*)d_in[12];
  const float* ae2 = (const float*)d_in[13];
  const float* b2  = (const float*)d_in[14];
  float* out = (float*)d_out;

  char* p = (char*)d_ws;
  auto alloc = [&](size_t b) { char* r = p; p += (b + 255) & ~(size_t)255; return r; };
  float*  scal   = (float*)alloc(256);
  float*  hbuf   = (float*)alloc((size_t)N_NODES * HC * 4);  // hA (layer1) then hB (layer2)
  float*  out1   = (float*)alloc((size_t)N_NODES * HC * 4);
  float*  a_s    = (float*)alloc((size_t)N_NODES * 4 * 4);
  float*  a_d    = (float*)alloc((size_t)N_NODES * 4 * 4);
  float4* alpha  = (float4*)alloc((size_t)E_TOT * 16);
  int*    counts = (int*)alloc((size_t)N_NODES * 4);
  int*    offs   = (int*)alloc((size_t)(N_NODES + 1) * 4);
  int*    cursor = (int*)alloc((size_t)N_NODES * 4);
  int*    esrc   = (int*)alloc((size_t)E_TOT * 4);
  int*    edst   = (int*)alloc((size_t)E_TOT * 4);
  float*  ewc    = (float*)alloc((size_t)E_TOT * 4);

  hipMemsetAsync(scal, 0, 256, stream);
  hipMemsetAsync(counts, 0, (size_t)N_NODES * 4, stream);

  int* flag = (int*)scal + 16;
  const int egrid = (E_TOT + 255) / 256;

  detect_kernel<<<1, 64, 0, stream>>>(ei, flag);
  reduce_sum_kernel<<<512, 256, 0, stream>>>(ew, scal, N_EDGES);
  prep_c_kernel<<<1, 256, 0, stream>>>(We1, ae1, We2, ae2, scal, 1.0f / N_EDGES);
  hist_kernel<<<egrid, 256, 0, stream>>>(ei, flag, counts);
  scan_kernel<<<1, 1024, 0, stream>>>(counts, offs, cursor, N_NODES, E_TOT);
  scatter_kernel<<<egrid, 256, 0, stream>>>(ei, flag, ew, scal, cursor, esrc, edst, ewc);

  const int ggrid = (N_NODES + GBM - 1) / GBM;
  // layer 1
  sgemm_kernel<<<ggrid, 256, 0, stream>>>(x, W1, hbuf, N_NODES, 256);
  attn_coef_kernel<<<N_NODES / 2, 256, 0, stream>>>(hbuf, as1, ad1, a_s, a_d, N_NODES);
  alpha_kernel<<<egrid, 256, 0, stream>>>(a_s, a_d, esrc, edst, ewc, scal + 4, alpha);
  aggregate_kernel<<<N_NODES, 128, 0, stream>>>(hbuf, alpha, offs, esrc, b1, out1, N_NODES);
  // layer 2
  sgemm_kernel<<<ggrid, 256, 0, stream>>>(out1, W2, hbuf, N_NODES, 128);
  attn_coef_kernel<<<N_NODES / 2, 256, 0, stream>>>(hbuf, as2, ad2, a_s, a_d, N_NODES);
  alpha_kernel<<<egrid, 256, 0, stream>>>(a_s, a_d, esrc, edst, ewc, scal + 8, alpha);
  aggregate_kernel<<<N_NODES, 128, 0, stream>>>(hbuf, alpha, offs, esrc, b2, out, N_NODES);
}

// Round 3
// 525.286 us; speedup vs baseline: 1.5076x; 1.5076x over previous
//
#include <hip/hip_runtime.h>

#define N_NODES 50000
#define N_EDGES 800000
#define E_TOT   850000   // N_EDGES + N_NODES self loops
#define HC 128
#define NEG_SLOPE 0.2f
#define TILE 128         // per-wave LDS edge tile (deg>TILE uses slow exact fallback)

// ---------------- helpers ----------------
__device__ __forceinline__ int edge_get(const void* eidx, int f64, long long i) {
  return f64 ? (int)((const long long*)eidx)[i] : ((const int*)eidx)[i];
}
__device__ __forceinline__ float selh(float4 q, int head) {
  float a = (head & 1) ? q.y : q.x;
  float b = (head & 1) ? q.w : q.z;
  return (head & 2) ? b : a;
}
__device__ __forceinline__ float4 alpha4(float4 as, float4 ad, float w, float4 c) {
  float4 r;
  r.x = as.x + ad.x + w * c.x; r.x = r.x > 0.f ? r.x : NEG_SLOPE * r.x;
  r.y = as.y + ad.y + w * c.y; r.y = r.y > 0.f ? r.y : NEG_SLOPE * r.y;
  r.z = as.z + ad.z + w * c.z; r.z = r.z > 0.f ? r.z : NEG_SLOPE * r.z;
  r.w = as.w + ad.w + w * c.w; r.w = r.w > 0.f ? r.w : NEG_SLOPE * r.w;
  return r;
}
__device__ __forceinline__ void wave_max4(float4& m) {
  #pragma unroll
  for (int o = 1; o < 64; o <<= 1) {
    m.x = fmaxf(m.x, __shfl_xor(m.x, o, 64));
    m.y = fmaxf(m.y, __shfl_xor(m.y, o, 64));
    m.z = fmaxf(m.z, __shfl_xor(m.z, o, 64));
    m.w = fmaxf(m.w, __shfl_xor(m.w, o, 64));
  }
}
__device__ __forceinline__ void wave_sum4(float4& s) {
  #pragma unroll
  for (int o = 1; o < 64; o <<= 1) {
    s.x += __shfl_xor(s.x, o, 64);
    s.y += __shfl_xor(s.y, o, 64);
    s.z += __shfl_xor(s.z, o, 64);
    s.w += __shfl_xor(s.w, o, 64);
  }
}

// ---------------- setup kernels ----------------
// probe whether edge_index buffer is int64 (all values in [0,N)) or int32
__global__ void detect_kernel(const void* eidx, int* flag) {
  const long long* p = (const long long*)eidx;
  long long v = p[threadIdx.x];
  int bad = (v < 0 || v >= N_NODES);
  unsigned long long anybad = __ballot(bad);
  if (threadIdx.x == 0) *flag = (anybad == 0ull);
}

__global__ __launch_bounds__(256) void reduce_sum_kernel(const float* __restrict__ w,
                                                         float* __restrict__ scal, int e) {
  __shared__ float sh[4];
  float s = 0.f;
  for (int i = blockIdx.x * blockDim.x + threadIdx.x; i < e; i += gridDim.x * blockDim.x)
    s += w[i];
  #pragma unroll
  for (int m = 32; m >= 1; m >>= 1) s += __shfl_xor(s, m, 64);
  int lane = threadIdx.x & 63, wv = threadIdx.x >> 6;
  if (lane == 0) sh[wv] = s;
  __syncthreads();
  if (threadIdx.x == 0) {
    float t = sh[0] + sh[1] + sh[2] + sh[3];
    atomicAdd(&scal[0], t);
  }
}

// scal layout (floats): [0]=sum(ew) [1]=mean [4..7]=c1 [8..11]=c2 ; ((int*)scal)[16]=int64-flag
__global__ void prep_c_kernel(const float* __restrict__ We1, const float* __restrict__ ae1,
                              const float* __restrict__ We2, const float* __restrict__ ae2,
                              float* __restrict__ scal, float inv_e) {
  int t = threadIdx.x;
  float p = (t < 128) ? We1[t] * ae1[t] : We2[t - 128] * ae2[t - 128];
  #pragma unroll
  for (int m = 16; m >= 1; m >>= 1) p += __shfl_xor(p, m, 32);
  if ((t & 31) == 0) {
    int hd = (t & 127) >> 5;
    if (t < 128) scal[4 + hd] = p; else scal[8 + hd] = p;
  }
  if (t == 0) scal[1] = scal[0] * inv_e;
}

__global__ void hist_kernel(const void* eidx, const int* __restrict__ flag,
                            int* __restrict__ counts) {
  int pidx = blockIdx.x * 256 + threadIdx.x;
  if (pidx >= E_TOT) return;
  int f = *flag;
  int d = (pidx < N_EDGES) ? edge_get(eidx, f, (long long)N_EDGES + pidx)
                           : (pidx - N_EDGES);
  atomicAdd(&counts[d], 1);
}

// single-block exclusive scan, shuffle-based (3 barriers per 8192-chunk)
__global__ __launch_bounds__(1024) void scan_kernel(const int* __restrict__ counts,
    int* __restrict__ offs, int* __restrict__ cursor, int n, int total) {
  __shared__ int wtot[16];
  __shared__ int woff[16];
  __shared__ int chunk_tot;
  int lane = threadIdx.x & 63, wv = threadIdx.x >> 6;
  int carry = 0;
  const int CHUNK = 8192;
  for (int base = 0; base < n; base += CHUNK) {
    int i0 = base + (int)threadIdx.x * 8;
    int v[8]; int local = 0;
    #pragma unroll
    for (int j = 0; j < 8; ++j) {
      int idx = i0 + j;
      v[j] = (idx < n) ? counts[idx] : 0;
      local += v[j];
    }
    int inc = local;                       // wave-inclusive scan
    #pragma unroll
    for (int off = 1; off < 64; off <<= 1) {
      int t = __shfl_up(inc, off, 64);
      if (lane >= off) inc += t;
    }
    if (lane == 63) wtot[wv] = inc;
    __syncthreads();
    if (wv == 0) {
      int tv = (lane < 16) ? wtot[lane] : 0;
      int ti = tv;
      #pragma unroll
      for (int o2 = 1; o2 < 16; o2 <<= 1) {
        int t2 = __shfl_up(ti, o2, 64);
        if (lane >= o2) ti += t2;
      }
      if (lane < 16) woff[lane] = ti - tv;
      if (lane == 15) chunk_tot = ti;
    }
    __syncthreads();
    int run = carry + woff[wv] + inc - local;
    #pragma unroll
    for (int j = 0; j < 8; ++j) {
      int idx = i0 + j;
      if (idx < n) { offs[idx] = run; cursor[idx] = run; }
      run += v[j];
    }
    carry += chunk_tot;
    __syncthreads();
  }
  if (threadIdx.x == 0) offs[n] = total;
}

__global__ void scatter_kernel(const void* eidx, const int* __restrict__ flag,
    const float* __restrict__ ew, const float* __restrict__ scal,
    int* __restrict__ cursor, int2* __restrict__ swp) {
  int pidx = blockIdx.x * 256 + threadIdx.x;
  if (pidx >= E_TOT) return;
  int f = *flag;
  int s, d; float w;
  if (pidx < N_EDGES) {
    s = edge_get(eidx, f, pidx);
    d = edge_get(eidx, f, (long long)N_EDGES + pidx);
    w = ew[pidx];
  } else {
    s = d = pidx - N_EDGES;
    w = scal[1];
  }
  int pos = atomicAdd(&cursor[d], 1);
  swp[pos] = make_int2(s, __float_as_int(w));
}

// ---------------- GEMM: C[M x 128] = A[M x K] * B[K x 128], fp32 ----------------
#define GBM 64
#define GBN 128
#define GBK 16
__global__ __launch_bounds__(256) void sgemm_kernel(const float* __restrict__ A,
    const float* __restrict__ B, float* __restrict__ C, int M, int K) {
  __shared__ float As[GBK][GBM + 4];
  __shared__ float Bs[GBK][GBN];
  int tid  = threadIdx.x;
  int bm   = blockIdx.x * GBM;
  int la_r = tid >> 2;
  int la_k = (tid & 3) << 2;
  int lb_r = tid >> 5;
  int lb_c = (tid & 31) << 2;
  int trow = tid >> 5;
  int tcol = tid & 31;
  float acc[8][4];
  #pragma unroll
  for (int i = 0; i < 8; ++i)
    #pragma unroll
    for (int j = 0; j < 4; ++j) acc[i][j] = 0.f;

  for (int k0 = 0; k0 < K; k0 += GBK) {
    int gr = bm + la_r;
    float4 av = make_float4(0.f, 0.f, 0.f, 0.f);
    if (gr < M) av = *(const float4*)(A + (size_t)gr * K + k0 + la_k);
    float4 bv0 = *(const float4*)(B + (size_t)(k0 + lb_r) * GBN + lb_c);
    float4 bv1 = *(const float4*)(B + (size_t)(k0 + lb_r + 8) * GBN + lb_c);
    __syncthreads();
    As[la_k + 0][la_r] = av.x; As[la_k + 1][la_r] = av.y;
    As[la_k + 2][la_r] = av.z; As[la_k + 3][la_r] = av.w;
    *(float4*)&Bs[lb_r][lb_c]     = bv0;
    *(float4*)&Bs[lb_r + 8][lb_c] = bv1;
    __syncthreads();
    #pragma unroll
    for (int kk = 0; kk < GBK; ++kk) {
      float4 a0 = *(const float4*)&As[kk][trow * 8];
      float4 a1 = *(const float4*)&As[kk][trow * 8 + 4];
      float4 b  = *(const float4*)&Bs[kk][tcol * 4];
      float av8[8] = {a0.x, a0.y, a0.z, a0.w, a1.x, a1.y, a1.z, a1.w};
      #pragma unroll
      for (int i = 0; i < 8; ++i) {
        acc[i][0] += av8[i] * b.x;
        acc[i][1] += av8[i] * b.y;
        acc[i][2] += av8[i] * b.z;
        acc[i][3] += av8[i] * b.w;
      }
    }
  }
  #pragma unroll
  for (int i = 0; i < 8; ++i) {
    int r = bm + trow * 8 + i;
    if (r < M)
      *(float4*)(C + (size_t)r * GBN + tcol * 4) =
          make_float4(acc[i][0], acc[i][1], acc[i][2], acc[i][3]);
  }
}

// ---------------- per-node attention coefficients ----------------
__global__ __launch_bounds__(256) void attn_coef_kernel(const float* __restrict__ h,
    const float* __restrict__ att_s, const float* __restrict__ att_d,
    float* __restrict__ a_s, float* __restrict__ a_d, int n) {
  int node = blockIdx.x * 2 + ((int)threadIdx.x >> 7);
  int d = threadIdx.x & 127;
  if (node >= n) return;
  float v  = h[(size_t)node * HC + d];
  float ps = v * att_s[d];
  float pd = v * att_d[d];
  #pragma unroll
  for (int m = 16; m >= 1; m >>= 1) {
    ps += __shfl_xor(ps, m, 32);
    pd += __shfl_xor(pd, m, 32);
  }
  if ((d & 31) == 0) {
    a_s[node * 4 + (d >> 5)] = ps;
    a_d[node * 4 + (d >> 5)] = pd;
  }
}

// ---------------- fused alpha + softmax + aggregation, one WAVE per node ----------------
// 256 threads = 4 waves = 4 nodes per block; no __syncthreads anywhere.
// Each lane owns output dims (2*lane, 2*lane+1); head = lane>>4.
__global__ __launch_bounds__(256) void aggregate_kernel(const float* __restrict__ h,
    const int2* __restrict__ swp, const int* __restrict__ offs,
    const float* __restrict__ a_s, const float* __restrict__ a_d,
    const float* __restrict__ cptr, const float* __restrict__ bias,
    float* __restrict__ out, int n) {
  __shared__ float4 wals[4][TILE];
  __shared__ int    ssh[4][TILE];
  int lane = threadIdx.x & 63;
  int wv   = threadIdx.x >> 6;
  int v    = blockIdx.x * 4 + wv;
  if (v >= n) return;
  int r0  = offs[v];
  int deg = offs[v + 1] - r0;
  float4 c  = *(const float4*)cptr;
  float4 ad = *(const float4*)(a_d + (size_t)v * 4);
  int head  = lane >> 4;
  float2 acc = make_float2(0.f, 0.f);
  const float* hb = h + 2 * lane;
  float4 mx = make_float4(-INFINITY, -INFINITY, -INFINITY, -INFINITY);
  float4 sm = make_float4(0.f, 0.f, 0.f, 0.f);

  if (deg <= TILE) {
    // pass A: alpha -> LDS, track max
    for (int i = lane; i < deg; i += 64) {
      int2 sw = swp[r0 + i];
      float w = __int_as_float(sw.y);
      float4 as = *(const float4*)(a_s + (size_t)sw.x * 4);
      float4 al = alpha4(as, ad, w, c);
      wals[wv][i] = al; ssh[wv][i] = sw.x;
      mx.x = fmaxf(mx.x, al.x); mx.y = fmaxf(mx.y, al.y);
      mx.z = fmaxf(mx.z, al.z); mx.w = fmaxf(mx.w, al.w);
    }
    wave_max4(mx);
    // pass B: e = exp(alpha - m) -> LDS, track sum
    for (int i = lane; i < deg; i += 64) {
      float4 al = wals[wv][i];
      float4 e;
      e.x = expf(al.x - mx.x); e.y = expf(al.y - mx.y);
      e.z = expf(al.z - mx.z); e.w = expf(al.w - mx.w);
      wals[wv][i] = e;
      sm.x += e.x; sm.y += e.y; sm.z += e.z; sm.w += e.w;
    }
    wave_sum4(sm);
    // pass C: batched gather-FMA, 8 loads in flight
    int i = 0;
    for (; i + 8 <= deg; i += 8) {
      float wr[8]; int sr[8];
      #pragma unroll
      for (int j = 0; j < 8; ++j) {
        sr[j] = ssh[wv][i + j];
        wr[j] = ((const float*)&wals[wv][i + j])[head];
      }
      float2 hv[8];
      #pragma unroll
      for (int j = 0; j < 8; ++j)
        hv[j] = *(const float2*)(hb + (size_t)sr[j] * HC);
      #pragma unroll
      for (int j = 0; j < 8; ++j) {
        acc.x += wr[j] * hv[j].x;
        acc.y += wr[j] * hv[j].y;
      }
    }
    for (; i < deg; ++i) {
      int s0 = ssh[wv][i];
      float w0 = ((const float*)&wals[wv][i])[head];
      float2 hvv = *(const float2*)(hb + (size_t)s0 * HC);
      acc.x += w0 * hvv.x;
      acc.y += w0 * hvv.y;
    }
  } else {
    // exact streaming fallback (deg > TILE): 3 passes, recompute alpha
    for (int i = lane; i < deg; i += 64) {
      int2 sw = swp[r0 + i];
      float4 as = *(const float4*)(a_s + (size_t)sw.x * 4);
      float4 al = alpha4(as, ad, __int_as_float(sw.y), c);
      mx.x = fmaxf(mx.x, al.x); mx.y = fmaxf(mx.y, al.y);
      mx.z = fmaxf(mx.z, al.z); mx.w = fmaxf(mx.w, al.w);
    }
    wave_max4(mx);
    for (int i = lane; i < deg; i += 64) {
      int2 sw = swp[r0 + i];
      float4 as = *(const float4*)(a_s + (size_t)sw.x * 4);
      float4 al = alpha4(as, ad, __int_as_float(sw.y), c);
      sm.x += expf(al.x - mx.x); sm.y += expf(al.y - mx.y);
      sm.z += expf(al.z - mx.z); sm.w += expf(al.w - mx.w);
    }
    wave_sum4(sm);
    float mxh = selh(mx, head);
    for (int i = 0; i < deg; ++i) {
      int2 sw = swp[r0 + i];                                   // uniform across wave
      float4 as = *(const float4*)(a_s + (size_t)sw.x * 4);
      float4 al = alpha4(as, ad, __int_as_float(sw.y), c);
      float e = expf(selh(al, head) - mxh);
      float2 hvv = *(const float2*)(hb + (size_t)sw.x * HC);
      acc.x += e * hvv.x;
      acc.y += e * hvv.y;
    }
  }
  float inv = 1.0f / selh(sm, head);
  float2 bb = *(const float2*)(bias + 2 * lane);
  float2 r;
  r.x = acc.x * inv + bb.x;
  r.y = acc.y * inv + bb.y;
  *(float2*)(out + (size_t)v * HC + 2 * lane) = r;
}

// ---------------- launcher ----------------
extern "C" void kernel_launch(void* const* d_in, const int* in_sizes, int n_in,
                              void* d_out, int out_size, void* d_ws, size_t ws_size,
                              hipStream_t stream) {
  const float* x   = (const float*)d_in[0];
  const void*  ei  = d_in[1];
  const float* ew  = (const float*)d_in[2];
  const float* W1  = (const float*)d_in[3];
  const float* as1 = (const float*)d_in[4];
  const float* ad1 = (const float*)d_in[5];
  const float* We1 = (const float*)d_in[6];
  const float* ae1 = (const float*)d_in[7];
  const float* b1  = (const float*)d_in[8];
  const float* W2  = (const float*)d_in[9];
  const float* as2 = (const float*)d_in[10];
  const float* ad2 = (const float*)d_in[11];
  const float* We2 = (const float*)d_in[12];
  const float* ae2 = (const float*)d_in[13];
  const float* b2  = (const float*)d_in[14];
  float* out = (float*)d_out;

  char* p = (char*)d_ws;
  auto alloc = [&](size_t b) { char* r = p; p += (b + 255) & ~(size_t)255; return r; };
  float*  scal   = (float*)alloc(256);
  float*  hbuf   = (float*)alloc((size_t)N_NODES * HC * 4);
  float*  out1   = (float*)alloc((size_t)N_NODES * HC * 4);
  float*  a_s    = (float*)alloc((size_t)N_NODES * 4 * 4);
  float*  a_d    = (float*)alloc((size_t)N_NODES * 4 * 4);
  int*    counts = (int*)alloc((size_t)N_NODES * 4);
  int*    offs   = (int*)alloc((size_t)(N_NODES + 1) * 4);
  int*    cursor = (int*)alloc((size_t)N_NODES * 4);
  int2*   swp    = (int2*)alloc((size_t)E_TOT * 8);

  hipMemsetAsync(scal, 0, 256, stream);
  hipMemsetAsync(counts, 0, (size_t)N_NODES * 4, stream);

  int* flag = (int*)scal + 16;
  const int egrid = (E_TOT + 255) / 256;

  detect_kernel<<<1, 64, 0, stream>>>(ei, flag);
  reduce_sum_kernel<<<512, 256, 0, stream>>>(ew, scal, N_EDGES);
  prep_c_kernel<<<1, 256, 0, stream>>>(We1, ae1, We2, ae2, scal, 1.0f / N_EDGES);
  hist_kernel<<<egrid, 256, 0, stream>>>(ei, flag, counts);
  scan_kernel<<<1, 1024, 0, stream>>>(counts, offs, cursor, N_NODES, E_TOT);
  scatter_kernel<<<egrid, 256, 0, stream>>>(ei, flag, ew, scal, cursor, swp);

  const int ggrid = (N_NODES + GBM - 1) / GBM;
  const int agrid = (N_NODES + 3) / 4;
  // layer 1
  sgemm_kernel<<<ggrid, 256, 0, stream>>>(x, W1, hbuf, N_NODES, 256);
  attn_coef_kernel<<<N_NODES / 2, 256, 0, stream>>>(hbuf, as1, ad1, a_s, a_d, N_NODES);
  aggregate_kernel<<<agrid, 256, 0, stream>>>(hbuf, swp, offs, a_s, a_d, scal + 4, b1,
                                              out1, N_NODES);
  // layer 2
  sgemm_kernel<<<ggrid, 256, 0, stream>>>(out1, W2, hbuf, N_NODES, 128);
  attn_coef_kernel<<<N_NODES / 2, 256, 0, stream>>>(hbuf, as2, ad2, a_s, a_d, N_NODES);
  aggregate_kernel<<<agrid, 256, 0, stream>>>(hbuf, swp, offs, a_s, a_d, scal + 8, b2,
                                              out, N_NODES);
}

// Round 4
// 436.838 us; speedup vs baseline: 1.8128x; 1.2025x over previous
//
#include <hip/hip_runtime.h>

#define N_NODES 50000
#define N_EDGES 800000
#define E_TOT   850000   // N_EDGES + N_NODES self loops
#define HC 128
#define NEG_SLOPE 0.2f
#define TILE 128         // per-wave LDS edge tile (deg>TILE uses slow exact fallback)
#define SBLK 256
#define NSCB ((N_NODES + SBLK - 1) / SBLK)   // 196 scan blocks

// ---------------- helpers ----------------
__device__ __forceinline__ int edge_get(const void* eidx, int f64, long long i) {
  return f64 ? (int)((const long long*)eidx)[i] : ((const int*)eidx)[i];
}
__device__ __forceinline__ float selh(float4 q, int head) {
  float a = (head & 1) ? q.y : q.x;
  float b = (head & 1) ? q.w : q.z;
  return (head & 2) ? b : a;
}
__device__ __forceinline__ float4 alpha4(float4 as, float4 ad, float w, float4 c) {
  float4 r;
  r.x = as.x + ad.x + w * c.x; r.x = r.x > 0.f ? r.x : NEG_SLOPE * r.x;
  r.y = as.y + ad.y + w * c.y; r.y = r.y > 0.f ? r.y : NEG_SLOPE * r.y;
  r.z = as.z + ad.z + w * c.z; r.z = r.z > 0.f ? r.z : NEG_SLOPE * r.z;
  r.w = as.w + ad.w + w * c.w; r.w = r.w > 0.f ? r.w : NEG_SLOPE * r.w;
  return r;
}
__device__ __forceinline__ void wave_max4(float4& m) {
  #pragma unroll
  for (int o = 1; o < 64; o <<= 1) {
    m.x = fmaxf(m.x, __shfl_xor(m.x, o, 64));
    m.y = fmaxf(m.y, __shfl_xor(m.y, o, 64));
    m.z = fmaxf(m.z, __shfl_xor(m.z, o, 64));
    m.w = fmaxf(m.w, __shfl_xor(m.w, o, 64));
  }
}
__device__ __forceinline__ void wave_sum4(float4& s) {
  #pragma unroll
  for (int o = 1; o < 64; o <<= 1) {
    s.x += __shfl_xor(s.x, o, 64);
    s.y += __shfl_xor(s.y, o, 64);
    s.z += __shfl_xor(s.z, o, 64);
    s.w += __shfl_xor(s.w, o, 64);
  }
}
// 256-thread block exclusive scan (4 waves). lds must hold >=4 ints. Two barriers.
__device__ __forceinline__ int block_scan_excl(int val, int* lds) {
  int lane = threadIdx.x & 63, wv = threadIdx.x >> 6;
  int inc = val;
  #pragma unroll
  for (int off = 1; off < 64; off <<= 1) {
    int t = __shfl_up(inc, off, 64);
    if (lane >= off) inc += t;
  }
  if (lane == 63) lds[wv] = inc;
  __syncthreads();
  if (threadIdx.x == 0) {
    int s = 0;
    #pragma unroll
    for (int i = 0; i < 4; ++i) { int t = lds[i]; lds[i] = s; s += t; }
  }
  __syncthreads();
  return lds[wv] + inc - val;
}

// ---------------- setup kernels ----------------
__global__ void detect_kernel(const void* eidx, int* flag) {
  const long long* p = (const long long*)eidx;
  long long v = p[threadIdx.x];
  int bad = (v < 0 || v >= N_NODES);
  unsigned long long anybad = __ballot(bad);
  if (threadIdx.x == 0) *flag = (anybad == 0ull);
}

__global__ __launch_bounds__(256) void reduce_sum_kernel(const float* __restrict__ w,
                                                         float* __restrict__ scal, int e) {
  __shared__ float sh[4];
  float s = 0.f;
  for (int i = blockIdx.x * blockDim.x + threadIdx.x; i < e; i += gridDim.x * blockDim.x)
    s += w[i];
  #pragma unroll
  for (int m = 32; m >= 1; m >>= 1) s += __shfl_xor(s, m, 64);
  int lane = threadIdx.x & 63, wv = threadIdx.x >> 6;
  if (lane == 0) sh[wv] = s;
  __syncthreads();
  if (threadIdx.x == 0) {
    float t = sh[0] + sh[1] + sh[2] + sh[3];
    atomicAdd(&scal[0], t);
  }
}

// scal layout (floats): [0]=sum(ew) [1]=mean [4..7]=c1 [8..11]=c2 ; ((int*)scal)[16]=int64-flag
__global__ void prep_c_kernel(const float* __restrict__ We1, const float* __restrict__ ae1,
                              const float* __restrict__ We2, const float* __restrict__ ae2,
                              float* __restrict__ scal, float inv_e) {
  int t = threadIdx.x;
  float p = (t < 128) ? We1[t] * ae1[t] : We2[t - 128] * ae2[t - 128];
  #pragma unroll
  for (int m = 16; m >= 1; m >>= 1) p += __shfl_xor(p, m, 32);
  if ((t & 31) == 0) {
    int hd = (t & 127) >> 5;
    if (t < 128) scal[4 + hd] = p; else scal[8 + hd] = p;
  }
  if (t == 0) scal[1] = scal[0] * inv_e;
}

__global__ void hist_kernel(const void* eidx, const int* __restrict__ flag,
                            int* __restrict__ counts) {
  int pidx = blockIdx.x * 256 + threadIdx.x;
  if (pidx >= E_TOT) return;
  int f = *flag;
  int d = (pidx < N_EDGES) ? edge_get(eidx, f, (long long)N_EDGES + pidx)
                           : (pidx - N_EDGES);
  atomicAdd(&counts[d], 1);
}

// ---- hierarchical scan: per-block sums -> scan sums -> per-block excl scan ----
__global__ __launch_bounds__(256) void scan1_kernel(const int* __restrict__ counts,
                                                    int* __restrict__ bsum) {
  int idx = blockIdx.x * SBLK + threadIdx.x;
  int v = (idx < N_NODES) ? counts[idx] : 0;
  #pragma unroll
  for (int o = 1; o < 64; o <<= 1) v += __shfl_xor(v, o, 64);
  __shared__ int sh[4];
  if ((threadIdx.x & 63) == 0) sh[threadIdx.x >> 6] = v;
  __syncthreads();
  if (threadIdx.x == 0) bsum[blockIdx.x] = sh[0] + sh[1] + sh[2] + sh[3];
}

__global__ __launch_bounds__(256) void scan2_kernel(const int* __restrict__ bsum,
                                                    int* __restrict__ bbase) {
  __shared__ int lds[4];
  int t = threadIdx.x;
  int v = (t < NSCB) ? bsum[t] : 0;
  int e = block_scan_excl(v, lds);
  if (t < NSCB) bbase[t] = e;
}

__global__ __launch_bounds__(256) void scan3_kernel(const int* __restrict__ counts,
    const int* __restrict__ bbase, int* __restrict__ offs, int* __restrict__ cursor) {
  __shared__ int lds[4];
  int idx = blockIdx.x * SBLK + threadIdx.x;
  int v = (idx < N_NODES) ? counts[idx] : 0;
  int e = block_scan_excl(v, lds) + bbase[blockIdx.x];
  if (idx < N_NODES) { offs[idx] = e; cursor[idx] = e; }
  if (idx == N_NODES) offs[N_NODES] = E_TOT;
}

__global__ void scatter_kernel(const void* eidx, const int* __restrict__ flag,
    const float* __restrict__ ew, const float* __restrict__ scal,
    int* __restrict__ cursor, int2* __restrict__ swp) {
  int pidx = blockIdx.x * 256 + threadIdx.x;
  if (pidx >= E_TOT) return;
  int f = *flag;
  int s, d; float w;
  if (pidx < N_EDGES) {
    s = edge_get(eidx, f, pidx);
    d = edge_get(eidx, f, (long long)N_EDGES + pidx);
    w = ew[pidx];
  } else {
    s = d = pidx - N_EDGES;
    w = scal[1];
  }
  int pos = atomicAdd(&cursor[d], 1);
  swp[pos] = make_int2(s, __float_as_int(w));
}

// ---- GEMM 128x128 tile + fused attention-coefficient epilogue ----
// C[M x 128] = A[M x K] * B[K x 128]; also a_s[r][h] = sum_d h[r,h,d]*att_s[h,d], same a_d.
#define GBM 128
#define GBN 128
#define GBK 16
__global__ __launch_bounds__(256) void sgemm_fused_kernel(const float* __restrict__ A,
    const float* __restrict__ B, const float* __restrict__ att_s,
    const float* __restrict__ att_d, float* __restrict__ C,
    float* __restrict__ a_s, float* __restrict__ a_d, int M, int K) {
  __shared__ float As[GBK][GBM + 4];   // transposed [k][m]
  __shared__ float Bs[GBK][GBN];
  int tid  = threadIdx.x;
  int bm   = blockIdx.x * GBM;
  int la_r = tid >> 1;            // 0..127
  int la_k = (tid & 1) << 3;      // 0 or 8
  int lb_r = tid >> 5;            // 0..7
  int lb_c = (tid & 31) << 2;     // 0..124
  int trow = tid >> 4;            // 0..15 -> rows trow*8..+7
  int tcol = tid & 15;            // 0..15 -> cols tcol*8..+7 (one head: tcol>>2)
  float acc[8][8];
  #pragma unroll
  for (int i = 0; i < 8; ++i)
    #pragma unroll
    for (int j = 0; j < 8; ++j) acc[i][j] = 0.f;

  for (int k0 = 0; k0 < K; k0 += GBK) {
    int gr = bm + la_r;
    float4 av0 = make_float4(0.f, 0.f, 0.f, 0.f), av1 = av0;
    if (gr < M) {
      av0 = *(const float4*)(A + (size_t)gr * K + k0 + la_k);
      av1 = *(const float4*)(A + (size_t)gr * K + k0 + la_k + 4);
    }
    float4 bv0 = *(const float4*)(B + (size_t)(k0 + lb_r) * GBN + lb_c);
    float4 bv1 = *(const float4*)(B + (size_t)(k0 + lb_r + 8) * GBN + lb_c);
    __syncthreads();
    As[la_k + 0][la_r] = av0.x; As[la_k + 1][la_r] = av0.y;
    As[la_k + 2][la_r] = av0.z; As[la_k + 3][la_r] = av0.w;
    As[la_k + 4][la_r] = av1.x; As[la_k + 5][la_r] = av1.y;
    As[la_k + 6][la_r] = av1.z; As[la_k + 7][la_r] = av1.w;
    *(float4*)&Bs[lb_r][lb_c]     = bv0;
    *(float4*)&Bs[lb_r + 8][lb_c] = bv1;
    __syncthreads();
    #pragma unroll
    for (int kk = 0; kk < GBK; ++kk) {
      float4 a0 = *(const float4*)&As[kk][trow * 8];
      float4 a1 = *(const float4*)&As[kk][trow * 8 + 4];
      float4 b0 = *(const float4*)&Bs[kk][tcol * 8];
      float4 b1 = *(const float4*)&Bs[kk][tcol * 8 + 4];
      float aa[8] = {a0.x, a0.y, a0.z, a0.w, a1.x, a1.y, a1.z, a1.w};
      float bb[8] = {b0.x, b0.y, b0.z, b0.w, b1.x, b1.y, b1.z, b1.w};
      #pragma unroll
      for (int i = 0; i < 8; ++i)
        #pragma unroll
        for (int j = 0; j < 8; ++j) acc[i][j] += aa[i] * bb[j];
    }
  }
  // att vectors for my 8 columns
  float4 s0 = *(const float4*)(att_s + tcol * 8);
  float4 s1 = *(const float4*)(att_s + tcol * 8 + 4);
  float4 d0 = *(const float4*)(att_d + tcol * 8);
  float4 d1 = *(const float4*)(att_d + tcol * 8 + 4);
  float sv[8] = {s0.x, s0.y, s0.z, s0.w, s1.x, s1.y, s1.z, s1.w};
  float dv[8] = {d0.x, d0.y, d0.z, d0.w, d1.x, d1.y, d1.z, d1.w};
  #pragma unroll
  for (int i = 0; i < 8; ++i) {
    int r = bm + trow * 8 + i;
    float ps = 0.f, pd = 0.f;
    #pragma unroll
    for (int j = 0; j < 8; ++j) { ps += acc[i][j] * sv[j]; pd += acc[i][j] * dv[j]; }
    ps += __shfl_xor(ps, 1, 64); ps += __shfl_xor(ps, 2, 64);
    pd += __shfl_xor(pd, 1, 64); pd += __shfl_xor(pd, 2, 64);
    if (r < M) {
      *(float4*)(C + (size_t)r * GBN + tcol * 8) =
          make_float4(acc[i][0], acc[i][1], acc[i][2], acc[i][3]);
      *(float4*)(C + (size_t)r * GBN + tcol * 8 + 4) =
          make_float4(acc[i][4], acc[i][5], acc[i][6], acc[i][7]);
      if ((tcol & 3) == 0) {
        a_s[(size_t)r * 4 + (tcol >> 2)] = ps;
        a_d[(size_t)r * 4 + (tcol >> 2)] = pd;
      }
    }
  }
}

// ---------------- fused alpha + softmax + aggregation, one WAVE per node ----------------
__global__ __launch_bounds__(256) void aggregate_kernel(const float* __restrict__ h,
    const int2* __restrict__ swp, const int* __restrict__ offs,
    const float* __restrict__ a_s, const float* __restrict__ a_d,
    const float* __restrict__ cptr, const float* __restrict__ bias,
    float* __restrict__ out, int n) {
  __shared__ float4 wals[4][TILE];
  __shared__ int    ssh[4][TILE];
  int lane = threadIdx.x & 63;
  int wv   = threadIdx.x >> 6;
  int v    = blockIdx.x * 4 + wv;
  if (v >= n) return;
  int r0  = offs[v];
  int deg = offs[v + 1] - r0;
  float4 c  = *(const float4*)cptr;
  float4 ad = *(const float4*)(a_d + (size_t)v * 4);
  int head  = lane >> 4;
  float2 acc = make_float2(0.f, 0.f);
  const float* hb = h + 2 * lane;
  float4 mx = make_float4(-INFINITY, -INFINITY, -INFINITY, -INFINITY);
  float4 sm = make_float4(0.f, 0.f, 0.f, 0.f);

  if (deg <= TILE) {
    for (int i = lane; i < deg; i += 64) {
      int2 sw = swp[r0 + i];
      float w = __int_as_float(sw.y);
      float4 as = *(const float4*)(a_s + (size_t)sw.x * 4);
      float4 al = alpha4(as, ad, w, c);
      wals[wv][i] = al; ssh[wv][i] = sw.x;
      mx.x = fmaxf(mx.x, al.x); mx.y = fmaxf(mx.y, al.y);
      mx.z = fmaxf(mx.z, al.z); mx.w = fmaxf(mx.w, al.w);
    }
    wave_max4(mx);
    for (int i = lane; i < deg; i += 64) {
      float4 al = wals[wv][i];
      float4 e;
      e.x = expf(al.x - mx.x); e.y = expf(al.y - mx.y);
      e.z = expf(al.z - mx.z); e.w = expf(al.w - mx.w);
      wals[wv][i] = e;
      sm.x += e.x; sm.y += e.y; sm.z += e.z; sm.w += e.w;
    }
    wave_sum4(sm);
    int i = 0;
    for (; i + 8 <= deg; i += 8) {
      float wr[8]; int sr[8];
      #pragma unroll
      for (int j = 0; j < 8; ++j) {
        sr[j] = ssh[wv][i + j];
        wr[j] = ((const float*)&wals[wv][i + j])[head];
      }
      float2 hv[8];
      #pragma unroll
      for (int j = 0; j < 8; ++j)
        hv[j] = *(const float2*)(hb + (size_t)sr[j] * HC);
      #pragma unroll
      for (int j = 0; j < 8; ++j) {
        acc.x += wr[j] * hv[j].x;
        acc.y += wr[j] * hv[j].y;
      }
    }
    for (; i < deg; ++i) {
      int s0 = ssh[wv][i];
      float w0 = ((const float*)&wals[wv][i])[head];
      float2 hvv = *(const float2*)(hb + (size_t)s0 * HC);
      acc.x += w0 * hvv.x;
      acc.y += w0 * hvv.y;
    }
  } else {
    // exact streaming fallback (deg > TILE)
    for (int i = lane; i < deg; i += 64) {
      int2 sw = swp[r0 + i];
      float4 as = *(const float4*)(a_s + (size_t)sw.x * 4);
      float4 al = alpha4(as, ad, __int_as_float(sw.y), c);
      mx.x = fmaxf(mx.x, al.x); mx.y = fmaxf(mx.y, al.y);
      mx.z = fmaxf(mx.z, al.z); mx.w = fmaxf(mx.w, al.w);
    }
    wave_max4(mx);
    for (int i = lane; i < deg; i += 64) {
      int2 sw = swp[r0 + i];
      float4 as = *(const float4*)(a_s + (size_t)sw.x * 4);
      float4 al = alpha4(as, ad, __int_as_float(sw.y), c);
      sm.x += expf(al.x - mx.x); sm.y += expf(al.y - mx.y);
      sm.z += expf(al.z - mx.z); sm.w += expf(al.w - mx.w);
    }
    wave_sum4(sm);
    float mxh = selh(mx, head);
    for (int i = 0; i < deg; ++i) {
      int2 sw = swp[r0 + i];
      float4 as = *(const float4*)(a_s + (size_t)sw.x * 4);
      float4 al = alpha4(as, ad, __int_as_float(sw.y), c);
      float e = expf(selh(al, head) - mxh);
      float2 hvv = *(const float2*)(hb + (size_t)sw.x * HC);
      acc.x += e * hvv.x;
      acc.y += e * hvv.y;
    }
  }
  float inv = 1.0f / selh(sm, head);
  float2 bb = *(const float2*)(bias + 2 * lane);
  float2 r;
  r.x = acc.x * inv + bb.x;
  r.y = acc.y * inv + bb.y;
  *(float2*)(out + (size_t)v * HC + 2 * lane) = r;
}

// ---------------- launcher ----------------
extern "C" void kernel_launch(void* const* d_in, const int* in_sizes, int n_in,
                              void* d_out, int out_size, void* d_ws, size_t ws_size,
                              hipStream_t stream) {
  const float* x   = (const float*)d_in[0];
  const void*  ei  = d_in[1];
  const float* ew  = (const float*)d_in[2];
  const float* W1  = (const float*)d_in[3];
  const float* as1 = (const float*)d_in[4];
  const float* ad1 = (const float*)d_in[5];
  const float* We1 = (const float*)d_in[6];
  const float* ae1 = (const float*)d_in[7];
  const float* b1  = (const float*)d_in[8];
  const float* W2  = (const float*)d_in[9];
  const float* as2 = (const float*)d_in[10];
  const float* ad2 = (const float*)d_in[11];
  const float* We2 = (const float*)d_in[12];
  const float* ae2 = (const float*)d_in[13];
  const float* b2  = (const float*)d_in[14];
  float* out = (float*)d_out;

  char* p = (char*)d_ws;
  auto alloc = [&](size_t b) { char* r = p; p += (b + 255) & ~(size_t)255; return r; };
  float*  scal   = (float*)alloc(256);
  float*  hbuf   = (float*)alloc((size_t)N_NODES * HC * 4);
  float*  out1   = (float*)alloc((size_t)N_NODES * HC * 4);
  float*  a_s    = (float*)alloc((size_t)N_NODES * 4 * 4);
  float*  a_d    = (float*)alloc((size_t)N_NODES * 4 * 4);
  int*    counts = (int*)alloc((size_t)N_NODES * 4);
  int*    offs   = (int*)alloc((size_t)(N_NODES + 1) * 4);
  int*    cursor = (int*)alloc((size_t)N_NODES * 4);
  int*    bsum   = (int*)alloc((size_t)NSCB * 4);
  int*    bbase  = (int*)alloc((size_t)NSCB * 4);
  int2*   swp    = (int2*)alloc((size_t)E_TOT * 8);

  hipMemsetAsync(scal, 0, 256, stream);
  hipMemsetAsync(counts, 0, (size_t)N_NODES * 4, stream);

  int* flag = (int*)scal + 16;
  const int egrid = (E_TOT + 255) / 256;

  detect_kernel<<<1, 64, 0, stream>>>(ei, flag);
  reduce_sum_kernel<<<512, 256, 0, stream>>>(ew, scal, N_EDGES);
  prep_c_kernel<<<1, 256, 0, stream>>>(We1, ae1, We2, ae2, scal, 1.0f / N_EDGES);
  hist_kernel<<<egrid, 256, 0, stream>>>(ei, flag, counts);
  scan1_kernel<<<NSCB, 256, 0, stream>>>(counts, bsum);
  scan2_kernel<<<1, 256, 0, stream>>>(bsum, bbase);
  scan3_kernel<<<NSCB, 256, 0, stream>>>(counts, bbase, offs, cursor);
  scatter_kernel<<<egrid, 256, 0, stream>>>(ei, flag, ew, scal, cursor, swp);

  const int ggrid = (N_NODES + GBM - 1) / GBM;
  const int agrid = (N_NODES + 3) / 4;
  // layer 1
  sgemm_fused_kernel<<<ggrid, 256, 0, stream>>>(x, W1, as1, ad1, hbuf, a_s, a_d,
                                                N_NODES, 256);
  aggregate_kernel<<<agrid, 256, 0, stream>>>(hbuf, swp, offs, a_s, a_d, scal + 4, b1,
                                              out1, N_NODES);
  // layer 2
  sgemm_fused_kernel<<<ggrid, 256, 0, stream>>>(out1, W2, as2, ad2, hbuf, a_s, a_d,
                                                N_NODES, 128);
  aggregate_kernel<<<agrid, 256, 0, stream>>>(hbuf, swp, offs, a_s, a_d, scal + 8, b2,
                                              out, N_NODES);
}

// Round 5
// 401.380 us; speedup vs baseline: 1.9729x; 1.0883x over previous
//
#include <hip/hip_runtime.h>
#include <hip/hip_fp16.h>

#define N_NODES 50000
#define N_EDGES 800000
#define E_TOT   850000   // N_EDGES + N_NODES self loops
#define HC 128
#define NEG_SLOPE 0.2f
#define TILE 128         // per-wave LDS edge tile (deg>TILE uses slow exact fallback)
#define SBLK 256
#define NSCB ((N_NODES + SBLK - 1) / SBLK)   // 196 scan blocks

// ---------------- helpers ----------------
__device__ __forceinline__ int edge_get(const void* eidx, int f64, long long i) {
  return f64 ? (int)((const long long*)eidx)[i] : ((const int*)eidx)[i];
}
__device__ __forceinline__ float selh(float4 q, int head) {
  float a = (head & 1) ? q.y : q.x;
  float b = (head & 1) ? q.w : q.z;
  return (head & 2) ? b : a;
}
__device__ __forceinline__ float4 alpha4(float4 as, float4 ad, float w, float4 c) {
  float4 r;
  r.x = as.x + ad.x + w * c.x; r.x = r.x > 0.f ? r.x : NEG_SLOPE * r.x;
  r.y = as.y + ad.y + w * c.y; r.y = r.y > 0.f ? r.y : NEG_SLOPE * r.y;
  r.z = as.z + ad.z + w * c.z; r.z = r.z > 0.f ? r.z : NEG_SLOPE * r.z;
  r.w = as.w + ad.w + w * c.w; r.w = r.w > 0.f ? r.w : NEG_SLOPE * r.w;
  return r;
}
__device__ __forceinline__ void wave_max4(float4& m) {
  #pragma unroll
  for (int o = 1; o < 64; o <<= 1) {
    m.x = fmaxf(m.x, __shfl_xor(m.x, o, 64));
    m.y = fmaxf(m.y, __shfl_xor(m.y, o, 64));
    m.z = fmaxf(m.z, __shfl_xor(m.z, o, 64));
    m.w = fmaxf(m.w, __shfl_xor(m.w, o, 64));
  }
}
__device__ __forceinline__ void wave_sum4(float4& s) {
  #pragma unroll
  for (int o = 1; o < 64; o <<= 1) {
    s.x += __shfl_xor(s.x, o, 64);
    s.y += __shfl_xor(s.y, o, 64);
    s.z += __shfl_xor(s.z, o, 64);
    s.w += __shfl_xor(s.w, o, 64);
  }
}
// 256-thread block exclusive scan (4 waves). lds must hold >=4 ints. Two barriers.
__device__ __forceinline__ int block_scan_excl(int val, int* lds) {
  int lane = threadIdx.x & 63, wv = threadIdx.x >> 6;
  int inc = val;
  #pragma unroll
  for (int off = 1; off < 64; off <<= 1) {
    int t = __shfl_up(inc, off, 64);
    if (lane >= off) inc += t;
  }
  if (lane == 63) lds[wv] = inc;
  __syncthreads();
  if (threadIdx.x == 0) {
    int s = 0;
    #pragma unroll
    for (int i = 0; i < 4; ++i) { int t = lds[i]; lds[i] = s; s += t; }
  }
  __syncthreads();
  return lds[wv] + inc - val;
}

// ---------------- setup kernels ----------------
__global__ void detect_kernel(const void* eidx, int* flag) {
  const long long* p = (const long long*)eidx;
  long long v = p[threadIdx.x];
  int bad = (v < 0 || v >= N_NODES);
  unsigned long long anybad = __ballot(bad);
  if (threadIdx.x == 0) *flag = (anybad == 0ull);
}

// scal layout (floats): [0]=sum(ew) [1]=mean [4..7]=c1 [8..11]=c2 ; ((int*)scal)[16]=int64-flag
// histogram of dst + sum of edge_weight folded into one edge pass
__global__ __launch_bounds__(256) void hist_ew_kernel(const void* eidx,
    const int* __restrict__ flag, const float* __restrict__ ew,
    int* __restrict__ counts, float* __restrict__ scal) {
  __shared__ float sh[4];
  int pidx = blockIdx.x * 256 + threadIdx.x;
  int f = *flag;
  float s = 0.f;
  if (pidx < E_TOT) {
    int d = (pidx < N_EDGES) ? edge_get(eidx, f, (long long)N_EDGES + pidx)
                             : (pidx - N_EDGES);
    atomicAdd(&counts[d], 1);
    if (pidx < N_EDGES) s = ew[pidx];
  }
  #pragma unroll
  for (int m = 32; m >= 1; m >>= 1) s += __shfl_xor(s, m, 64);
  int lane = threadIdx.x & 63, wv = threadIdx.x >> 6;
  if (lane == 0) sh[wv] = s;
  __syncthreads();
  if (threadIdx.x == 0) atomicAdd(&scal[0], sh[0] + sh[1] + sh[2] + sh[3]);
}

// ---- hierarchical scan: per-block sums -> scan sums (+prep consts) -> per-block scan ----
__global__ __launch_bounds__(256) void scan1_kernel(const int* __restrict__ counts,
                                                    int* __restrict__ bsum) {
  int idx = blockIdx.x * SBLK + threadIdx.x;
  int v = (idx < N_NODES) ? counts[idx] : 0;
  #pragma unroll
  for (int o = 1; o < 64; o <<= 1) v += __shfl_xor(v, o, 64);
  __shared__ int sh[4];
  if ((threadIdx.x & 63) == 0) sh[threadIdx.x >> 6] = v;
  __syncthreads();
  if (threadIdx.x == 0) bsum[blockIdx.x] = sh[0] + sh[1] + sh[2] + sh[3];
}

__global__ __launch_bounds__(256) void scan2_prep_kernel(const int* __restrict__ bsum,
    int* __restrict__ bbase, const float* __restrict__ We1, const float* __restrict__ ae1,
    const float* __restrict__ We2, const float* __restrict__ ae2,
    float* __restrict__ scal, float inv_e) {
  __shared__ int lds[4];
  int t = threadIdx.x;
  int v = (t < NSCB) ? bsum[t] : 0;
  int e = block_scan_excl(v, lds);
  if (t < NSCB) bbase[t] = e;
  // prep: c1/c2 head dot-products + edge-weight mean
  float p = (t < 128) ? We1[t] * ae1[t] : We2[t - 128] * ae2[t - 128];
  #pragma unroll
  for (int m = 16; m >= 1; m >>= 1) p += __shfl_xor(p, m, 32);
  if ((t & 31) == 0) {
    int hd = (t & 127) >> 5;
    if (t < 128) scal[4 + hd] = p; else scal[8 + hd] = p;
  }
  if (t == 0) scal[1] = scal[0] * inv_e;
}

__global__ __launch_bounds__(256) void scan3_kernel(const int* __restrict__ counts,
    const int* __restrict__ bbase, int* __restrict__ offs, int* __restrict__ cursor) {
  __shared__ int lds[4];
  int idx = blockIdx.x * SBLK + threadIdx.x;
  int v = (idx < N_NODES) ? counts[idx] : 0;
  int e = block_scan_excl(v, lds) + bbase[blockIdx.x];
  if (idx < N_NODES) { offs[idx] = e; cursor[idx] = e; }
  if (idx == N_NODES) offs[N_NODES] = E_TOT;
}

__global__ void scatter_kernel(const void* eidx, const int* __restrict__ flag,
    const float* __restrict__ ew, const float* __restrict__ scal,
    int* __restrict__ cursor, int2* __restrict__ swp) {
  int pidx = blockIdx.x * 256 + threadIdx.x;
  if (pidx >= E_TOT) return;
  int f = *flag;
  int s, d; float w;
  if (pidx < N_EDGES) {
    s = edge_get(eidx, f, pidx);
    d = edge_get(eidx, f, (long long)N_EDGES + pidx);
    w = ew[pidx];
  } else {
    s = d = pidx - N_EDGES;
    w = scal[1];
  }
  int pos = atomicAdd(&cursor[d], 1);
  swp[pos] = make_int2(s, __float_as_int(w));
}

// ---- GEMM 128x128 tile + fused attention-coefficient epilogue; h stored fp16 ----
// h16[M x 128] = fp16(A[M x K] * B[K x 128]); a_s[r][h] = sum_d h[r,h,d]*att_s[h,d], same a_d.
// h16 is ONLY consumed by the aggregate gather (att coefs fused here; layer-2 GEMM reads
// the fp32 aggregate output) -> fp16 halves the dominant L2-fill traffic, err ~5e-4 rel.
#define GBM 128
#define GBN 128
#define GBK 16
__global__ __launch_bounds__(256) void sgemm_fused_kernel(const float* __restrict__ A,
    const float* __restrict__ B, const float* __restrict__ att_s,
    const float* __restrict__ att_d, __half* __restrict__ h16,
    float* __restrict__ a_s, float* __restrict__ a_d, int M, int K) {
  __shared__ float As[GBK][GBM + 4];   // transposed [k][m]
  __shared__ float Bs[GBK][GBN];
  int tid  = threadIdx.x;
  int bm   = blockIdx.x * GBM;
  int la_r = tid >> 1;            // 0..127
  int la_k = (tid & 1) << 3;      // 0 or 8
  int lb_r = tid >> 5;            // 0..7
  int lb_c = (tid & 31) << 2;     // 0..124
  int trow = tid >> 4;            // 0..15 -> rows trow*8..+7
  int tcol = tid & 15;            // 0..15 -> cols tcol*8..+7 (one head: tcol>>2)
  float acc[8][8];
  #pragma unroll
  for (int i = 0; i < 8; ++i)
    #pragma unroll
    for (int j = 0; j < 8; ++j) acc[i][j] = 0.f;

  for (int k0 = 0; k0 < K; k0 += GBK) {
    int gr = bm + la_r;
    float4 av0 = make_float4(0.f, 0.f, 0.f, 0.f), av1 = av0;
    if (gr < M) {
      av0 = *(const float4*)(A + (size_t)gr * K + k0 + la_k);
      av1 = *(const float4*)(A + (size_t)gr * K + k0 + la_k + 4);
    }
    float4 bv0 = *(const float4*)(B + (size_t)(k0 + lb_r) * GBN + lb_c);
    float4 bv1 = *(const float4*)(B + (size_t)(k0 + lb_r + 8) * GBN + lb_c);
    __syncthreads();
    As[la_k + 0][la_r] = av0.x; As[la_k + 1][la_r] = av0.y;
    As[la_k + 2][la_r] = av0.z; As[la_k + 3][la_r] = av0.w;
    As[la_k + 4][la_r] = av1.x; As[la_k + 5][la_r] = av1.y;
    As[la_k + 6][la_r] = av1.z; As[la_k + 7][la_r] = av1.w;
    *(float4*)&Bs[lb_r][lb_c]     = bv0;
    *(float4*)&Bs[lb_r + 8][lb_c] = bv1;
    __syncthreads();
    #pragma unroll
    for (int kk = 0; kk < GBK; ++kk) {
      float4 a0 = *(const float4*)&As[kk][trow * 8];
      float4 a1 = *(const float4*)&As[kk][trow * 8 + 4];
      float4 b0 = *(const float4*)&Bs[kk][tcol * 8];
      float4 b1 = *(const float4*)&Bs[kk][tcol * 8 + 4];
      float aa[8] = {a0.x, a0.y, a0.z, a0.w, a1.x, a1.y, a1.z, a1.w};
      float bb[8] = {b0.x, b0.y, b0.z, b0.w, b1.x, b1.y, b1.z, b1.w};
      #pragma unroll
      for (int i = 0; i < 8; ++i)
        #pragma unroll
        for (int j = 0; j < 8; ++j) acc[i][j] += aa[i] * bb[j];
    }
  }
  // att vectors for my 8 columns
  float4 s0 = *(const float4*)(att_s + tcol * 8);
  float4 s1 = *(const float4*)(att_s + tcol * 8 + 4);
  float4 d0 = *(const float4*)(att_d + tcol * 8);
  float4 d1 = *(const float4*)(att_d + tcol * 8 + 4);
  float sv[8] = {s0.x, s0.y, s0.z, s0.w, s1.x, s1.y, s1.z, s1.w};
  float dv[8] = {d0.x, d0.y, d0.z, d0.w, d1.x, d1.y, d1.z, d1.w};
  #pragma unroll
  for (int i = 0; i < 8; ++i) {
    int r = bm + trow * 8 + i;
    float ps = 0.f, pd = 0.f;
    #pragma unroll
    for (int j = 0; j < 8; ++j) { ps += acc[i][j] * sv[j]; pd += acc[i][j] * dv[j]; }
    ps += __shfl_xor(ps, 1, 64); ps += __shfl_xor(ps, 2, 64);
    pd += __shfl_xor(pd, 1, 64); pd += __shfl_xor(pd, 2, 64);
    if (r < M) {
      __half hh[8];
      #pragma unroll
      for (int j = 0; j < 8; ++j) hh[j] = __float2half(acc[i][j]);
      *(float4*)(h16 + (size_t)r * GBN + tcol * 8) = *(float4*)hh;
      if ((tcol & 3) == 0) {
        a_s[(size_t)r * 4 + (tcol >> 2)] = ps;
        a_d[(size_t)r * 4 + (tcol >> 2)] = pd;
      }
    }
  }
}

// ---------------- fused alpha + softmax + aggregation, one WAVE per node ----------------
// Each lane owns output dims (2*lane, 2*lane+1); head = lane>>4. h gathered as fp16.
__global__ __launch_bounds__(256) void aggregate_kernel(const __half* __restrict__ h,
    const int2* __restrict__ swp, const int* __restrict__ offs,
    const float* __restrict__ a_s, const float* __restrict__ a_d,
    const float* __restrict__ cptr, const float* __restrict__ bias,
    float* __restrict__ out, int n) {
  __shared__ float4 wals[4][TILE];
  __shared__ int    ssh[4][TILE];
  int lane = threadIdx.x & 63;
  int wv   = threadIdx.x >> 6;
  int v    = blockIdx.x * 4 + wv;
  if (v >= n) return;
  int r0  = offs[v];
  int deg = offs[v + 1] - r0;
  float4 c  = *(const float4*)cptr;
  float4 ad = *(const float4*)(a_d + (size_t)v * 4);
  int head  = lane >> 4;
  float2 acc = make_float2(0.f, 0.f);
  const __half* hb = h + 2 * lane;
  float4 mx = make_float4(-INFINITY, -INFINITY, -INFINITY, -INFINITY);
  float4 sm = make_float4(0.f, 0.f, 0.f, 0.f);

  if (deg <= TILE) {
    for (int i = lane; i < deg; i += 64) {
      int2 sw = swp[r0 + i];
      float w = __int_as_float(sw.y);
      float4 as = *(const float4*)(a_s + (size_t)sw.x * 4);
      float4 al = alpha4(as, ad, w, c);
      wals[wv][i] = al; ssh[wv][i] = sw.x;
      mx.x = fmaxf(mx.x, al.x); mx.y = fmaxf(mx.y, al.y);
      mx.z = fmaxf(mx.z, al.z); mx.w = fmaxf(mx.w, al.w);
    }
    wave_max4(mx);
    for (int i = lane; i < deg; i += 64) {
      float4 al = wals[wv][i];
      float4 e;
      e.x = expf(al.x - mx.x); e.y = expf(al.y - mx.y);
      e.z = expf(al.z - mx.z); e.w = expf(al.w - mx.w);
      wals[wv][i] = e;
      sm.x += e.x; sm.y += e.y; sm.z += e.z; sm.w += e.w;
    }
    wave_sum4(sm);
    int i = 0;
    for (; i + 8 <= deg; i += 8) {
      float wr[8]; int sr[8];
      #pragma unroll
      for (int j = 0; j < 8; ++j) {
        sr[j] = ssh[wv][i + j];
        wr[j] = ((const float*)&wals[wv][i + j])[head];
      }
      __half2 hv[8];
      #pragma unroll
      for (int j = 0; j < 8; ++j)
        hv[j] = *(const __half2*)(hb + (size_t)sr[j] * HC);
      #pragma unroll
      for (int j = 0; j < 8; ++j) {
        acc.x += wr[j] * __low2float(hv[j]);
        acc.y += wr[j] * __high2float(hv[j]);
      }
    }
    for (; i < deg; ++i) {
      int s0 = ssh[wv][i];
      float w0 = ((const float*)&wals[wv][i])[head];
      __half2 hvv = *(const __half2*)(hb + (size_t)s0 * HC);
      acc.x += w0 * __low2float(hvv);
      acc.y += w0 * __high2float(hvv);
    }
  } else {
    // exact streaming fallback (deg > TILE)
    for (int i = lane; i < deg; i += 64) {
      int2 sw = swp[r0 + i];
      float4 as = *(const float4*)(a_s + (size_t)sw.x * 4);
      float4 al = alpha4(as, ad, __int_as_float(sw.y), c);
      mx.x = fmaxf(mx.x, al.x); mx.y = fmaxf(mx.y, al.y);
      mx.z = fmaxf(mx.z, al.z); mx.w = fmaxf(mx.w, al.w);
    }
    wave_max4(mx);
    for (int i = lane; i < deg; i += 64) {
      int2 sw = swp[r0 + i];
      float4 as = *(const float4*)(a_s + (size_t)sw.x * 4);
      float4 al = alpha4(as, ad, __int_as_float(sw.y), c);
      sm.x += expf(al.x - mx.x); sm.y += expf(al.y - mx.y);
      sm.z += expf(al.z - mx.z); sm.w += expf(al.w - mx.w);
    }
    wave_sum4(sm);
    float mxh = selh(mx, head);
    for (int i = 0; i < deg; ++i) {
      int2 sw = swp[r0 + i];
      float4 as = *(const float4*)(a_s + (size_t)sw.x * 4);
      float4 al = alpha4(as, ad, __int_as_float(sw.y), c);
      float e = expf(selh(al, head) - mxh);
      __half2 hvv = *(const __half2*)(hb + (size_t)sw.x * HC);
      acc.x += e * __low2float(hvv);
      acc.y += e * __high2float(hvv);
    }
  }
  float inv = 1.0f / selh(sm, head);
  float2 bb = *(const float2*)(bias + 2 * lane);
  float2 r;
  r.x = acc.x * inv + bb.x;
  r.y = acc.y * inv + bb.y;
  *(float2*)(out + (size_t)v * HC + 2 * lane) = r;
}

// ---------------- launcher ----------------
extern "C" void kernel_launch(void* const* d_in, const int* in_sizes, int n_in,
                              void* d_out, int out_size, void* d_ws, size_t ws_size,
                              hipStream_t stream) {
  const float* x   = (const float*)d_in[0];
  const void*  ei  = d_in[1];
  const float* ew  = (const float*)d_in[2];
  const float* W1  = (const float*)d_in[3];
  const float* as1 = (const float*)d_in[4];
  const float* ad1 = (const float*)d_in[5];
  const float* We1 = (const float*)d_in[6];
  const float* ae1 = (const float*)d_in[7];
  const float* b1  = (const float*)d_in[8];
  const float* W2  = (const float*)d_in[9];
  const float* as2 = (const float*)d_in[10];
  const float* ad2 = (const float*)d_in[11];
  const float* We2 = (const float*)d_in[12];
  const float* ae2 = (const float*)d_in[13];
  const float* b2  = (const float*)d_in[14];
  float* out = (float*)d_out;

  char* p = (char*)d_ws;
  auto alloc = [&](size_t b) { char* r = p; p += (b + 255) & ~(size_t)255; return r; };
  float*  scal   = (float*)alloc(256);
  __half* h16    = (__half*)alloc((size_t)N_NODES * HC * 2);
  float*  out1   = (float*)alloc((size_t)N_NODES * HC * 4);
  float*  a_s    = (float*)alloc((size_t)N_NODES * 4 * 4);
  float*  a_d    = (float*)alloc((size_t)N_NODES * 4 * 4);
  int*    counts = (int*)alloc((size_t)N_NODES * 4);
  int*    offs   = (int*)alloc((size_t)(N_NODES + 1) * 4);
  int*    cursor = (int*)alloc((size_t)N_NODES * 4);
  int*    bsum   = (int*)alloc((size_t)NSCB * 4);
  int*    bbase  = (int*)alloc((size_t)NSCB * 4);
  int2*   swp    = (int2*)alloc((size_t)E_TOT * 8);

  hipMemsetAsync(scal, 0, 256, stream);
  hipMemsetAsync(counts, 0, (size_t)N_NODES * 4, stream);

  int* flag = (int*)scal + 16;
  const int egrid = (E_TOT + 255) / 256;

  detect_kernel<<<1, 64, 0, stream>>>(ei, flag);
  hist_ew_kernel<<<egrid, 256, 0, stream>>>(ei, flag, ew, counts, scal);
  scan1_kernel<<<NSCB, 256, 0, stream>>>(counts, bsum);
  scan2_prep_kernel<<<1, 256, 0, stream>>>(bsum, bbase, We1, ae1, We2, ae2, scal,
                                           1.0f / N_EDGES);
  scan3_kernel<<<NSCB, 256, 0, stream>>>(counts, bbase, offs, cursor);
  scatter_kernel<<<egrid, 256, 0, stream>>>(ei, flag, ew, scal, cursor, swp);

  const int ggrid = (N_NODES + GBM - 1) / GBM;
  const int agrid = (N_NODES + 3) / 4;
  // layer 1
  sgemm_fused_kernel<<<ggrid, 256, 0, stream>>>(x, W1, as1, ad1, h16, a_s, a_d,
                                                N_NODES, 256);
  aggregate_kernel<<<agrid, 256, 0, stream>>>(h16, swp, offs, a_s, a_d, scal + 4, b1,
                                              out1, N_NODES);
  // layer 2
  sgemm_fused_kernel<<<ggrid, 256, 0, stream>>>(out1, W2, as2, ad2, h16, a_s, a_d,
                                                N_NODES, 128);
  aggregate_kernel<<<agrid, 256, 0, stream>>>(h16, swp, offs, a_s, a_d, scal + 8, b2,
                                              out, N_NODES);
}

// Round 6
// 379.637 us; speedup vs baseline: 2.0859x; 1.0573x over previous
//
#include <hip/hip_runtime.h>
#include <hip/hip_fp16.h>

#define N_NODES 50000
#define N_EDGES 800000
#define E_TOT   850000   // N_EDGES + N_NODES self loops
#define HC 128
#define NEG_SLOPE 0.2f
#define TILE 128         // per-wave LDS edge tile (deg>TILE uses slow exact fallback)
#define SBLK 256
#define NSCB ((N_NODES + SBLK - 1) / SBLK)   // 196 scan blocks
#define KP 40            // LDS k-pitch (bf16 elems): 32 + 8 pad -> 2-way conflicts only

typedef unsigned short u16;
typedef __attribute__((ext_vector_type(8))) short short8;
typedef __attribute__((ext_vector_type(4))) float f32x4;

// ---------------- helpers ----------------
__device__ __forceinline__ int edge_get(const void* eidx, int f64, long long i) {
  return f64 ? (int)((const long long*)eidx)[i] : ((const int*)eidx)[i];
}
__device__ __forceinline__ float selh(float4 q, int head) {
  float a = (head & 1) ? q.y : q.x;
  float b = (head & 1) ? q.w : q.z;
  return (head & 2) ? b : a;
}
__device__ __forceinline__ float4 alpha4(float4 as, float4 ad, float w, float4 c) {
  float4 r;
  r.x = as.x + ad.x + w * c.x; r.x = r.x > 0.f ? r.x : NEG_SLOPE * r.x;
  r.y = as.y + ad.y + w * c.y; r.y = r.y > 0.f ? r.y : NEG_SLOPE * r.y;
  r.z = as.z + ad.z + w * c.z; r.z = r.z > 0.f ? r.z : NEG_SLOPE * r.z;
  r.w = as.w + ad.w + w * c.w; r.w = r.w > 0.f ? r.w : NEG_SLOPE * r.w;
  return r;
}
__device__ __forceinline__ void wave_max4(float4& m) {
  #pragma unroll
  for (int o = 1; o < 64; o <<= 1) {
    m.x = fmaxf(m.x, __shfl_xor(m.x, o, 64));
    m.y = fmaxf(m.y, __shfl_xor(m.y, o, 64));
    m.z = fmaxf(m.z, __shfl_xor(m.z, o, 64));
    m.w = fmaxf(m.w, __shfl_xor(m.w, o, 64));
  }
}
__device__ __forceinline__ void wave_sum4(float4& s) {
  #pragma unroll
  for (int o = 1; o < 64; o <<= 1) {
    s.x += __shfl_xor(s.x, o, 64);
    s.y += __shfl_xor(s.y, o, 64);
    s.z += __shfl_xor(s.z, o, 64);
    s.w += __shfl_xor(s.w, o, 64);
  }
}
// split fp32 into bf16 hi + bf16 lo (truncation; residual ~2^-16 relative)
__device__ __forceinline__ void splitbf(float v, u16& h, u16& l) {
  unsigned b = __float_as_uint(v);
  h = (u16)(b >> 16);
  float lo = v - __uint_as_float(b & 0xFFFF0000u);
  l = (u16)(__float_as_uint(lo) >> 16);
}
// 256-thread block exclusive scan (4 waves).
__device__ __forceinline__ int block_scan_excl(int val, int* lds) {
  int lane = threadIdx.x & 63, wv = threadIdx.x >> 6;
  int inc = val;
  #pragma unroll
  for (int off = 1; off < 64; off <<= 1) {
    int t = __shfl_up(inc, off, 64);
    if (lane >= off) inc += t;
  }
  if (lane == 63) lds[wv] = inc;
  __syncthreads();
  if (threadIdx.x == 0) {
    int s = 0;
    #pragma unroll
    for (int i = 0; i < 4; ++i) { int t = lds[i]; lds[i] = s; s += t; }
  }
  __syncthreads();
  return lds[wv] + inc - val;
}

// ---------------- setup kernels ----------------
__global__ void detect_kernel(const void* eidx, int* flag) {
  const long long* p = (const long long*)eidx;
  long long v = p[threadIdx.x];
  int bad = (v < 0 || v >= N_NODES);
  unsigned long long anybad = __ballot(bad);
  if (threadIdx.x == 0) *flag = (anybad == 0ull);
}

// scal layout (floats): [0]=sum(ew) [1]=mean [4..7]=c1 [8..11]=c2 ; ((int*)scal)[16]=int64-flag
__global__ __launch_bounds__(256) void hist_ew_kernel(const void* eidx,
    const int* __restrict__ flag, const float* __restrict__ ew,
    int* __restrict__ counts, float* __restrict__ scal) {
  __shared__ float sh[4];
  int pidx = blockIdx.x * 256 + threadIdx.x;
  int f = *flag;
  float s = 0.f;
  if (pidx < E_TOT) {
    int d = (pidx < N_EDGES) ? edge_get(eidx, f, (long long)N_EDGES + pidx)
                             : (pidx - N_EDGES);
    atomicAdd(&counts[d], 1);
    if (pidx < N_EDGES) s = ew[pidx];
  }
  #pragma unroll
  for (int m = 32; m >= 1; m >>= 1) s += __shfl_xor(s, m, 64);
  int lane = threadIdx.x & 63, wv = threadIdx.x >> 6;
  if (lane == 0) sh[wv] = s;
  __syncthreads();
  if (threadIdx.x == 0) atomicAdd(&scal[0], sh[0] + sh[1] + sh[2] + sh[3]);
}

__global__ __launch_bounds__(256) void scan1_kernel(const int* __restrict__ counts,
                                                    int* __restrict__ bsum) {
  int idx = blockIdx.x * SBLK + threadIdx.x;
  int v = (idx < N_NODES) ? counts[idx] : 0;
  #pragma unroll
  for (int o = 1; o < 64; o <<= 1) v += __shfl_xor(v, o, 64);
  __shared__ int sh[4];
  if ((threadIdx.x & 63) == 0) sh[threadIdx.x >> 6] = v;
  __syncthreads();
  if (threadIdx.x == 0) bsum[blockIdx.x] = sh[0] + sh[1] + sh[2] + sh[3];
}

__global__ __launch_bounds__(256) void scan2_prep_kernel(const int* __restrict__ bsum,
    int* __restrict__ bbase, const float* __restrict__ We1, const float* __restrict__ ae1,
    const float* __restrict__ We2, const float* __restrict__ ae2,
    float* __restrict__ scal, float inv_e) {
  __shared__ int lds[4];
  int t = threadIdx.x;
  int v = (t < NSCB) ? bsum[t] : 0;
  int e = block_scan_excl(v, lds);
  if (t < NSCB) bbase[t] = e;
  float p = (t < 128) ? We1[t] * ae1[t] : We2[t - 128] * ae2[t - 128];
  #pragma unroll
  for (int m = 16; m >= 1; m >>= 1) p += __shfl_xor(p, m, 32);
  if ((t & 31) == 0) {
    int hd = (t & 127) >> 5;
    if (t < 128) scal[4 + hd] = p; else scal[8 + hd] = p;
  }
  if (t == 0) scal[1] = scal[0] * inv_e;
}

__global__ __launch_bounds__(256) void scan3_kernel(const int* __restrict__ counts,
    const int* __restrict__ bbase, int* __restrict__ offs, int* __restrict__ cursor) {
  __shared__ int lds[4];
  int idx = blockIdx.x * SBLK + threadIdx.x;
  int v = (idx < N_NODES) ? counts[idx] : 0;
  int e = block_scan_excl(v, lds) + bbase[blockIdx.x];
  if (idx < N_NODES) { offs[idx] = e; cursor[idx] = e; }
  if (idx == N_NODES) offs[N_NODES] = E_TOT;
}

__global__ void scatter_kernel(const void* eidx, const int* __restrict__ flag,
    const float* __restrict__ ew, const float* __restrict__ scal,
    int* __restrict__ cursor, int2* __restrict__ swp) {
  int pidx = blockIdx.x * 256 + threadIdx.x;
  if (pidx >= E_TOT) return;
  int f = *flag;
  int s, d; float w;
  if (pidx < N_EDGES) {
    s = edge_get(eidx, f, pidx);
    d = edge_get(eidx, f, (long long)N_EDGES + pidx);
    w = ew[pidx];
  } else {
    s = d = pidx - N_EDGES;
    w = scal[1];
  }
  int pos = atomicAdd(&cursor[d], 1);
  swp[pos] = make_int2(s, __float_as_int(w));
}

// ---- pre-split W^T into bf16 hi/lo: wt[ch][k] = split(W[k][ch]) ----
__global__ __launch_bounds__(256) void wprep_kernel(const float* __restrict__ W1,
    const float* __restrict__ W2, u16* __restrict__ w1h, u16* __restrict__ w1l,
    u16* __restrict__ w2h, u16* __restrict__ w2l) {
  int i = blockIdx.x * 256 + threadIdx.x;
  if (i < 128 * 256) {
    int ch = i >> 8, k = i & 255;
    u16 h, l; splitbf(W1[k * 128 + ch], h, l);
    w1h[i] = h; w1l[i] = l;
  } else if (i < 128 * 256 + 128 * 128) {
    int j = i - 128 * 256;
    int ch = j >> 7, k = j & 127;
    u16 h, l; splitbf(W2[k * 128 + ch], h, l);
    w2h[j] = h; w2l[j] = l;
  }
}

// ---- split-bf16 MFMA GEMM: h^T = W^T(128 x K) * x^T(K x M), output h16[M x 128] fp16 ----
// 3-product fp32 emulation: acc += hiW*hiX + hiW*loX + loW*hiX (loW*loX ~2^-32, dropped).
// Block: 128 chs x 128 nodes, 4 waves (2 ch-blocks x 2 node-blocks), BK=32.
// A-operand rows (lane&15) = ch; B-operand cols (lane&15) = node; k-slot mapping applied
// identically to both operands, so any HW k-permutation cancels.
// C/D frag: col=lane&15 (node), row=(lane>>4)*4+reg (ch)  [HW-verified mapping].
__global__ __launch_bounds__(256) void mfma_gemm_kernel(const float* __restrict__ A,
    const u16* __restrict__ wth, const u16* __restrict__ wtl,
    __half* __restrict__ h16, int M, int K) {
  __shared__ u16 Xh[128][KP], Xl[128][KP];   // [node][k]
  __shared__ u16 Gh[128][KP], Gl[128][KP];   // [ch][k]  (W^T)
  int tid  = threadIdx.x;
  int lane = tid & 63, wid = tid >> 6;
  int q = lane >> 4, r = lane & 15;
  int wm = wid >> 1, wn = wid & 1;
  int node0 = blockIdx.x * 128;
  int srow  = tid >> 1;             // staging row 0..127
  int skoff = (tid & 1) << 4;       // 0 or 16 (k elems)

  f32x4 acc[4][4];
  #pragma unroll
  for (int i = 0; i < 4; ++i)
    #pragma unroll
    for (int j = 0; j < 4; ++j) acc[i][j] = (f32x4)0.f;

  for (int k0 = 0; k0 < K; k0 += 32) {
    // global loads (before barrier)
    int gn = node0 + srow;
    float xv[16];
    if (gn < M) {
      const float* src = A + (size_t)gn * K + k0 + skoff;
      #pragma unroll
      for (int j = 0; j < 4; ++j) {
        float4 t = *(const float4*)(src + j * 4);
        xv[j * 4 + 0] = t.x; xv[j * 4 + 1] = t.y;
        xv[j * 4 + 2] = t.z; xv[j * 4 + 3] = t.w;
      }
    } else {
      #pragma unroll
      for (int j = 0; j < 16; ++j) xv[j] = 0.f;
    }
    const u16* wsrc = wth + (size_t)srow * K + k0 + skoff;
    const u16* lsrc = wtl + (size_t)srow * K + k0 + skoff;
    short8 wh0 = *(const short8*)wsrc;
    short8 wh1 = *(const short8*)(wsrc + 8);
    short8 wl0 = *(const short8*)lsrc;
    short8 wl1 = *(const short8*)(lsrc + 8);
    __syncthreads();
    short8 xh0, xh1, xl0, xl1;
    #pragma unroll
    for (int j = 0; j < 8; ++j) {
      u16 h, l;
      splitbf(xv[j], h, l);     xh0[j] = (short)h; xl0[j] = (short)l;
      splitbf(xv[j + 8], h, l); xh1[j] = (short)h; xl1[j] = (short)l;
    }
    *(short8*)&Xh[srow][skoff]     = xh0;
    *(short8*)&Xh[srow][skoff + 8] = xh1;
    *(short8*)&Xl[srow][skoff]     = xl0;
    *(short8*)&Xl[srow][skoff + 8] = xl1;
    *(short8*)&Gh[srow][skoff]     = wh0;
    *(short8*)&Gh[srow][skoff + 8] = wh1;
    *(short8*)&Gl[srow][skoff]     = wl0;
    *(short8*)&Gl[srow][skoff + 8] = wl1;
    __syncthreads();
    short8 ah[4], al[4], bh[4], bl[4];
    #pragma unroll
    for (int mi = 0; mi < 4; ++mi) {
      int row = wm * 64 + mi * 16 + r;
      ah[mi] = *(const short8*)&Gh[row][q * 8];
      al[mi] = *(const short8*)&Gl[row][q * 8];
    }
    #pragma unroll
    for (int ni = 0; ni < 4; ++ni) {
      int row = wn * 64 + ni * 16 + r;
      bh[ni] = *(const short8*)&Xh[row][q * 8];
      bl[ni] = *(const short8*)&Xl[row][q * 8];
    }
    #pragma unroll
    for (int mi = 0; mi < 4; ++mi)
      #pragma unroll
      for (int ni = 0; ni < 4; ++ni) {
        acc[mi][ni] = __builtin_amdgcn_mfma_f32_16x16x32_bf16(ah[mi], bh[ni], acc[mi][ni], 0, 0, 0);
        acc[mi][ni] = __builtin_amdgcn_mfma_f32_16x16x32_bf16(ah[mi], bl[ni], acc[mi][ni], 0, 0, 0);
        acc[mi][ni] = __builtin_amdgcn_mfma_f32_16x16x32_bf16(al[mi], bh[ni], acc[mi][ni], 0, 0, 0);
      }
  }
  // epilogue: lane holds D[ch = wm*64+mi*16+q*4+t][node = node0+wn*64+ni*16+r]
  #pragma unroll
  for (int ni = 0; ni < 4; ++ni) {
    int node = node0 + wn * 64 + ni * 16 + r;
    if (node < M) {
      #pragma unroll
      for (int mi = 0; mi < 4; ++mi) {
        int chb = wm * 64 + mi * 16 + q * 4;
        __half hh[4];
        hh[0] = __float2half(acc[mi][ni][0]);
        hh[1] = __float2half(acc[mi][ni][1]);
        hh[2] = __float2half(acc[mi][ni][2]);
        hh[3] = __float2half(acc[mi][ni][3]);
        *(float2*)(h16 + (size_t)node * HC + chb) = *(float2*)hh;
      }
    }
  }
}

// ---- per-node attention coefficients from fp16 h (one wave per node) ----
__global__ __launch_bounds__(256) void attn_coef16_kernel(const __half* __restrict__ h,
    const float* __restrict__ att_s, const float* __restrict__ att_d,
    float* __restrict__ a_s, float* __restrict__ a_d, int n) {
  int lane = threadIdx.x & 63, wid = threadIdx.x >> 6;
  int node = blockIdx.x * 4 + wid;
  if (node >= n) return;
  __half2 hv = *(const __half2*)(h + (size_t)node * HC + 2 * lane);
  float v0 = __low2float(hv), v1 = __high2float(hv);
  float2 as2 = *(const float2*)(att_s + 2 * lane);
  float2 ad2 = *(const float2*)(att_d + 2 * lane);
  float ps = v0 * as2.x + v1 * as2.y;
  float pd = v0 * ad2.x + v1 * ad2.y;
  #pragma unroll
  for (int o = 1; o < 16; o <<= 1) {
    ps += __shfl_xor(ps, o, 64);
    pd += __shfl_xor(pd, o, 64);
  }
  if ((lane & 15) == 0) {
    a_s[(size_t)node * 4 + (lane >> 4)] = ps;
    a_d[(size_t)node * 4 + (lane >> 4)] = pd;
  }
}

// ---------------- fused alpha + softmax + aggregation, one WAVE per node ----------------
__global__ __launch_bounds__(256) void aggregate_kernel(const __half* __restrict__ h,
    const int2* __restrict__ swp, const int* __restrict__ offs,
    const float* __restrict__ a_s, const float* __restrict__ a_d,
    const float* __restrict__ cptr, const float* __restrict__ bias,
    float* __restrict__ out, int n) {
  __shared__ float4 wals[4][TILE];
  __shared__ int    ssh[4][TILE];
  int lane = threadIdx.x & 63;
  int wv   = threadIdx.x >> 6;
  int v    = blockIdx.x * 4 + wv;
  if (v >= n) return;
  int r0  = offs[v];
  int deg = offs[v + 1] - r0;
  float4 c  = *(const float4*)cptr;
  float4 ad = *(const float4*)(a_d + (size_t)v * 4);
  int head  = lane >> 4;
  float2 acc = make_float2(0.f, 0.f);
  const __half* hb = h + 2 * lane;
  float4 mx = make_float4(-INFINITY, -INFINITY, -INFINITY, -INFINITY);
  float4 sm = make_float4(0.f, 0.f, 0.f, 0.f);

  if (deg <= TILE) {
    for (int i = lane; i < deg; i += 64) {
      int2 sw = swp[r0 + i];
      float w = __int_as_float(sw.y);
      float4 as = *(const float4*)(a_s + (size_t)sw.x * 4);
      float4 al = alpha4(as, ad, w, c);
      wals[wv][i] = al; ssh[wv][i] = sw.x;
      mx.x = fmaxf(mx.x, al.x); mx.y = fmaxf(mx.y, al.y);
      mx.z = fmaxf(mx.z, al.z); mx.w = fmaxf(mx.w, al.w);
    }
    wave_max4(mx);
    for (int i = lane; i < deg; i += 64) {
      float4 al = wals[wv][i];
      float4 e;
      e.x = expf(al.x - mx.x); e.y = expf(al.y - mx.y);
      e.z = expf(al.z - mx.z); e.w = expf(al.w - mx.w);
      wals[wv][i] = e;
      sm.x += e.x; sm.y += e.y; sm.z += e.z; sm.w += e.w;
    }
    wave_sum4(sm);
    int i = 0;
    for (; i + 8 <= deg; i += 8) {
      float wr[8]; int sr[8];
      #pragma unroll
      for (int j = 0; j < 8; ++j) {
        sr[j] = ssh[wv][i + j];
        wr[j] = ((const float*)&wals[wv][i + j])[head];
      }
      __half2 hv[8];
      #pragma unroll
      for (int j = 0; j < 8; ++j)
        hv[j] = *(const __half2*)(hb + (size_t)sr[j] * HC);
      #pragma unroll
      for (int j = 0; j < 8; ++j) {
        acc.x += wr[j] * __low2float(hv[j]);
        acc.y += wr[j] * __high2float(hv[j]);
      }
    }
    for (; i < deg; ++i) {
      int s0 = ssh[wv][i];
      float w0 = ((const float*)&wals[wv][i])[head];
      __half2 hvv = *(const __half2*)(hb + (size_t)s0 * HC);
      acc.x += w0 * __low2float(hvv);
      acc.y += w0 * __high2float(hvv);
    }
  } else {
    for (int i = lane; i < deg; i += 64) {
      int2 sw = swp[r0 + i];
      float4 as = *(const float4*)(a_s + (size_t)sw.x * 4);
      float4 al = alpha4(as, ad, __int_as_float(sw.y), c);
      mx.x = fmaxf(mx.x, al.x); mx.y = fmaxf(mx.y, al.y);
      mx.z = fmaxf(mx.z, al.z); mx.w = fmaxf(mx.w, al.w);
    }
    wave_max4(mx);
    for (int i = lane; i < deg; i += 64) {
      int2 sw = swp[r0 + i];
      float4 as = *(const float4*)(a_s + (size_t)sw.x * 4);
      float4 al = alpha4(as, ad, __int_as_float(sw.y), c);
      sm.x += expf(al.x - mx.x); sm.y += expf(al.y - mx.y);
      sm.z += expf(al.z - mx.z); sm.w += expf(al.w - mx.w);
    }
    wave_sum4(sm);
    float mxh = selh(mx, head);
    for (int i = 0; i < deg; ++i) {
      int2 sw = swp[r0 + i];
      float4 as = *(const float4*)(a_s + (size_t)sw.x * 4);
      float4 al = alpha4(as, ad, __int_as_float(sw.y), c);
      float e = expf(selh(al, head) - mxh);
      __half2 hvv = *(const __half2*)(hb + (size_t)sw.x * HC);
      acc.x += e * __low2float(hvv);
      acc.y += e * __high2float(hvv);
    }
  }
  float inv = 1.0f / selh(sm, head);
  float2 bb = *(const float2*)(bias + 2 * lane);
  float2 r;
  r.x = acc.x * inv + bb.x;
  r.y = acc.y * inv + bb.y;
  *(float2*)(out + (size_t)v * HC + 2 * lane) = r;
}

// ---------------- launcher ----------------
extern "C" void kernel_launch(void* const* d_in, const int* in_sizes, int n_in,
                              void* d_out, int out_size, void* d_ws, size_t ws_size,
                              hipStream_t stream) {
  const float* x   = (const float*)d_in[0];
  const void*  ei  = d_in[1];
  const float* ew  = (const float*)d_in[2];
  const float* W1  = (const float*)d_in[3];
  const float* as1 = (const float*)d_in[4];
  const float* ad1 = (const float*)d_in[5];
  const float* We1 = (const float*)d_in[6];
  const float* ae1 = (const float*)d_in[7];
  const float* b1  = (const float*)d_in[8];
  const float* W2  = (const float*)d_in[9];
  const float* as2 = (const float*)d_in[10];
  const float* ad2 = (const float*)d_in[11];
  const float* We2 = (const float*)d_in[12];
  const float* ae2 = (const float*)d_in[13];
  const float* b2  = (const float*)d_in[14];
  float* out = (float*)d_out;

  char* p = (char*)d_ws;
  auto alloc = [&](size_t b) { char* r = p; p += (b + 255) & ~(size_t)255; return r; };
  float*  scal   = (float*)alloc(256);
  __half* h16    = (__half*)alloc((size_t)N_NODES * HC * 2);
  float*  out1   = (float*)alloc((size_t)N_NODES * HC * 4);
  float*  a_s    = (float*)alloc((size_t)N_NODES * 4 * 4);
  float*  a_d    = (float*)alloc((size_t)N_NODES * 4 * 4);
  int*    counts = (int*)alloc((size_t)N_NODES * 4);
  int*    offs   = (int*)alloc((size_t)(N_NODES + 1) * 4);
  int*    cursor = (int*)alloc((size_t)N_NODES * 4);
  int*    bsum   = (int*)alloc((size_t)NSCB * 4);
  int*    bbase  = (int*)alloc((size_t)NSCB * 4);
  int2*   swp    = (int2*)alloc((size_t)E_TOT * 8);
  u16*    w1h    = (u16*)alloc((size_t)128 * 256 * 2);
  u16*    w1l    = (u16*)alloc((size_t)128 * 256 * 2);
  u16*    w2h    = (u16*)alloc((size_t)128 * 128 * 2);
  u16*    w2l    = (u16*)alloc((size_t)128 * 128 * 2);

  hipMemsetAsync(scal, 0, 256, stream);
  hipMemsetAsync(counts, 0, (size_t)N_NODES * 4, stream);

  int* flag = (int*)scal + 16;
  const int egrid = (E_TOT + 255) / 256;

  detect_kernel<<<1, 64, 0, stream>>>(ei, flag);
  hist_ew_kernel<<<egrid, 256, 0, stream>>>(ei, flag, ew, counts, scal);
  scan1_kernel<<<NSCB, 256, 0, stream>>>(counts, bsum);
  scan2_prep_kernel<<<1, 256, 0, stream>>>(bsum, bbase, We1, ae1, We2, ae2, scal,
                                           1.0f / N_EDGES);
  scan3_kernel<<<NSCB, 256, 0, stream>>>(counts, bbase, offs, cursor);
  scatter_kernel<<<egrid, 256, 0, stream>>>(ei, flag, ew, scal, cursor, swp);
  wprep_kernel<<<192, 256, 0, stream>>>(W1, W2, w1h, w1l, w2h, w2l);

  const int ggrid = (N_NODES + 127) / 128;
  const int agrid = (N_NODES + 3) / 4;
  // layer 1
  mfma_gemm_kernel<<<ggrid, 256, 0, stream>>>(x, w1h, w1l, h16, N_NODES, 256);
  attn_coef16_kernel<<<agrid, 256, 0, stream>>>(h16, as1, ad1, a_s, a_d, N_NODES);
  aggregate_kernel<<<agrid, 256, 0, stream>>>(h16, swp, offs, a_s, a_d, scal + 4, b1,
                                              out1, N_NODES);
  // layer 2
  mfma_gemm_kernel<<<ggrid, 256, 0, stream>>>(out1, w2h, w2l, h16, N_NODES, 128);
  attn_coef16_kernel<<<agrid, 256, 0, stream>>>(h16, as2, ad2, a_s, a_d, N_NODES);
  aggregate_kernel<<<agrid, 256, 0, stream>>>(h16, swp, offs, a_s, a_d, scal + 8, b2,
                                              out, N_NODES);
}

// Round 7
// 298.703 us; speedup vs baseline: 2.6511x; 1.2710x over previous
//
#include <hip/hip_runtime.h>
#include <hip/hip_fp16.h>

#define N_NODES 50000
#define N_EDGES 800000
#define E_TOT   850000   // N_EDGES + N_NODES self loops
#define HC 128
#define NEG_SLOPE 0.2f
#define TILE 128         // per-wave LDS edge tile (deg>TILE uses slow exact fallback)
#define KP 40            // MFMA LDS k-pitch (bf16 elems): 32 + 8 pad
#define CH 4096                              // edges per sort chunk
#define NCH ((E_TOT + CH - 1) / CH)          // 208 chunks  (< 256 required)
#define NP  ((N_NODES + 255) >> 8)           // 196 partitions of 256 dsts (< 256 required)

typedef unsigned short u16;
typedef __attribute__((ext_vector_type(8))) short short8;
typedef __attribute__((ext_vector_type(4))) float f32x4;

// ---------------- helpers ----------------
__device__ __forceinline__ int edge_get(const void* eidx, int f64, long long i) {
  return f64 ? (int)((const long long*)eidx)[i] : ((const int*)eidx)[i];
}
__device__ __forceinline__ float selh(float4 q, int head) {
  float a = (head & 1) ? q.y : q.x;
  float b = (head & 1) ? q.w : q.z;
  return (head & 2) ? b : a;
}
__device__ __forceinline__ float4 alpha4(float4 as, float4 ad, float w, float4 c) {
  float4 r;
  r.x = as.x + ad.x + w * c.x; r.x = r.x > 0.f ? r.x : NEG_SLOPE * r.x;
  r.y = as.y + ad.y + w * c.y; r.y = r.y > 0.f ? r.y : NEG_SLOPE * r.y;
  r.z = as.z + ad.z + w * c.z; r.z = r.z > 0.f ? r.z : NEG_SLOPE * r.z;
  r.w = as.w + ad.w + w * c.w; r.w = r.w > 0.f ? r.w : NEG_SLOPE * r.w;
  return r;
}
__device__ __forceinline__ void wave_max4(float4& m) {
  #pragma unroll
  for (int o = 1; o < 64; o <<= 1) {
    m.x = fmaxf(m.x, __shfl_xor(m.x, o, 64));
    m.y = fmaxf(m.y, __shfl_xor(m.y, o, 64));
    m.z = fmaxf(m.z, __shfl_xor(m.z, o, 64));
    m.w = fmaxf(m.w, __shfl_xor(m.w, o, 64));
  }
}
__device__ __forceinline__ void wave_sum4(float4& s) {
  #pragma unroll
  for (int o = 1; o < 64; o <<= 1) {
    s.x += __shfl_xor(s.x, o, 64);
    s.y += __shfl_xor(s.y, o, 64);
    s.z += __shfl_xor(s.z, o, 64);
    s.w += __shfl_xor(s.w, o, 64);
  }
}
__device__ __forceinline__ void splitbf(float v, u16& h, u16& l) {
  unsigned b = __float_as_uint(v);
  h = (u16)(b >> 16);
  float lo = v - __uint_as_float(b & 0xFFFF0000u);
  l = (u16)(__float_as_uint(lo) >> 16);
}
// 256-thread block exclusive scan (4 waves).
__device__ __forceinline__ int block_scan_excl(int val, int* lds) {
  int lane = threadIdx.x & 63, wv = threadIdx.x >> 6;
  int inc = val;
  #pragma unroll
  for (int off = 1; off < 64; off <<= 1) {
    int t = __shfl_up(inc, off, 64);
    if (lane >= off) inc += t;
  }
  if (lane == 63) lds[wv] = inc;
  __syncthreads();
  if (threadIdx.x == 0) {
    int s = 0;
    #pragma unroll
    for (int i = 0; i < 4; ++i) { int t = lds[i]; lds[i] = s; s += t; }
  }
  __syncthreads();
  return lds[wv] + inc - val;
}

// ---------------- setup ----------------
__global__ void detect_kernel(const void* eidx, int* flag) {
  const long long* p = (const long long*)eidx;
  long long v = p[threadIdx.x];
  int bad = (v < 0 || v >= N_NODES);
  unsigned long long anybad = __ballot(bad);
  if (threadIdx.x == 0) *flag = (anybad == 0ull);
}

// ---- CSR build, pass A: per-chunk partition histogram (LDS only) + ew sum ----
// scal layout (floats): [0]=sum(ew) [1]=mean [4..7]=c1 [8..11]=c2 ; ((int*)scal)[16]=flag
__global__ __launch_bounds__(256) void chunkhist_kernel(const void* eidx,
    const int* __restrict__ flag, const float* __restrict__ ew,
    int* __restrict__ cnt, float* __restrict__ scal) {
  __shared__ int hist[NP];
  __shared__ float sh[4];
  int c = blockIdx.x, tid = threadIdx.x;
  for (int i = tid; i < NP; i += 256) hist[i] = 0;
  __syncthreads();
  int f = *flag;
  int i0 = c * CH, i1 = min(i0 + CH, E_TOT);
  float s = 0.f;
  for (int i = i0 + tid; i < i1; i += 256) {
    int d = (i < N_EDGES) ? edge_get(eidx, f, (long long)N_EDGES + i) : (i - N_EDGES);
    atomicAdd(&hist[d >> 8], 1);
    if (i < N_EDGES) s += ew[i];
  }
  #pragma unroll
  for (int m = 32; m >= 1; m >>= 1) s += __shfl_xor(s, m, 64);
  int lane = tid & 63, wv = tid >> 6;
  if (lane == 0) sh[wv] = s;
  __syncthreads();
  for (int i = tid; i < NP; i += 256) cnt[c * NP + i] = hist[i];
  if (tid == 0) atomicAdd(&scal[0], sh[0] + sh[1] + sh[2] + sh[3]);
}

// ---- pass B1: per-partition column scan over chunks ----
__global__ __launch_bounds__(256) void colscan_kernel(const int* __restrict__ cnt,
    int* __restrict__ base_rel, int* __restrict__ ptot) {
  __shared__ int lds[4];
  int p = blockIdx.x, c = threadIdx.x;
  int v = (c < NCH) ? cnt[c * NP + p] : 0;
  int e = block_scan_excl(v, lds);
  if (c < NCH) base_rel[c * NP + p] = e;
  if (c == 255) ptot[p] = e;          // v==0 for c>=NCH -> e at 255 == column total
}

// ---- pass B2: scan partition totals -> pofs; fold in prep constants ----
__global__ __launch_bounds__(256) void pscan_prep_kernel(const int* __restrict__ ptot,
    int* __restrict__ pofs, const float* __restrict__ We1, const float* __restrict__ ae1,
    const float* __restrict__ We2, const float* __restrict__ ae2,
    float* __restrict__ scal, float inv_e) {
  __shared__ int lds[4];
  int t = threadIdx.x;
  int v = (t < NP) ? ptot[t] : 0;
  int e = block_scan_excl(v, lds);
  if (t <= NP) pofs[t] = e;           // t==NP (v=0) -> e == E_TOT
  float p = (t < 128) ? We1[t] * ae1[t] : We2[t - 128] * ae2[t - 128];
  #pragma unroll
  for (int m = 16; m >= 1; m >>= 1) p += __shfl_xor(p, m, 32);
  if ((t & 31) == 0) {
    int hd = (t & 127) >> 5;
    if (t < 128) scal[4 + hd] = p; else scal[8 + hd] = p;
  }
  if (t == 0) scal[1] = scal[0] * inv_e;
}

// ---- pass C: partition edges (block-exclusive contiguous runs per partition) ----
// record: x = (dst<<16)|src  (N_NODES<65536), y = bits(w)
__global__ __launch_bounds__(256) void partition_kernel(const void* eidx,
    const int* __restrict__ flag, const float* __restrict__ ew,
    const float* __restrict__ scal, const int* __restrict__ base_rel,
    const int* __restrict__ pofs, int2* __restrict__ swp1) {
  __shared__ int cur[NP];
  int c = blockIdx.x, tid = threadIdx.x;
  for (int i = tid; i < NP; i += 256) cur[i] = base_rel[c * NP + i] + pofs[i];
  __syncthreads();
  int f = *flag;
  float wmean = scal[1];
  int i0 = c * CH, i1 = min(i0 + CH, E_TOT);
  for (int i = i0 + tid; i < i1; i += 256) {
    int s, d; float w;
    if (i < N_EDGES) {
      s = edge_get(eidx, f, i);
      d = edge_get(eidx, f, (long long)N_EDGES + i);
      w = ew[i];
    } else {
      s = d = i - N_EDGES;
      w = wmean;
    }
    int pos = atomicAdd(&cur[d >> 8], 1);
    swp1[pos] = make_int2((int)(((unsigned)d << 16) | (unsigned)s), __float_as_int(w));
  }
}

// ---- pass D: per-partition local counting sort (one block per partition) ----
__global__ __launch_bounds__(256) void localsort_kernel(const int2* __restrict__ swp1,
    const int* __restrict__ pofs, int* __restrict__ offs, int2* __restrict__ swp2) {
  __shared__ int lhist[256];
  __shared__ int lds[4];
  int p = blockIdx.x, tid = threadIdx.x;
  int r0 = pofs[p], r1 = pofs[p + 1];
  lhist[tid] = 0;
  __syncthreads();
  for (int i = r0 + tid; i < r1; i += 256) {
    unsigned key = (unsigned)swp1[i].x;
    atomicAdd(&lhist[(key >> 16) & 255u], 1);
  }
  __syncthreads();
  int v = lhist[tid];
  int e = block_scan_excl(v, lds);
  int node = (p << 8) + tid;
  if (node < N_NODES) offs[node] = r0 + e;
  if (p == 0 && tid == 0) offs[N_NODES] = E_TOT;
  lhist[tid] = e;                      // relative cursor
  __syncthreads();
  for (int i = r0 + tid; i < r1; i += 256) {
    int2 rec = swp1[i];
    unsigned key = (unsigned)rec.x;
    int pos = r0 + atomicAdd(&lhist[(key >> 16) & 255u], 1);
    swp2[pos] = make_int2((int)(key & 0xFFFFu), rec.y);
  }
}

// ---- pre-split W^T into bf16 hi/lo: wt[ch][k] = split(W[k][ch]) ----
__global__ __launch_bounds__(256) void wprep_kernel(const float* __restrict__ W1,
    const float* __restrict__ W2, u16* __restrict__ w1h, u16* __restrict__ w1l,
    u16* __restrict__ w2h, u16* __restrict__ w2l) {
  int i = blockIdx.x * 256 + threadIdx.x;
  if (i < 128 * 256) {
    int ch = i >> 8, k = i & 255;
    u16 h, l; splitbf(W1[k * 128 + ch], h, l);
    w1h[i] = h; w1l[i] = l;
  } else if (i < 128 * 256 + 128 * 128) {
    int j = i - 128 * 256;
    int ch = j >> 7, k = j & 127;
    u16 h, l; splitbf(W2[k * 128 + ch], h, l);
    w2h[j] = h; w2l[j] = l;
  }
}

// ---- split-bf16 MFMA GEMM: h^T = W^T(128 x K) * x^T(K x M), output h16[M x 128] fp16 ----
__global__ __launch_bounds__(256) void mfma_gemm_kernel(const float* __restrict__ A,
    const u16* __restrict__ wth, const u16* __restrict__ wtl,
    __half* __restrict__ h16, int M, int K) {
  __shared__ u16 Xh[128][KP], Xl[128][KP];   // [node][k]
  __shared__ u16 Gh[128][KP], Gl[128][KP];   // [ch][k]  (W^T)
  int tid  = threadIdx.x;
  int lane = tid & 63, wid = tid >> 6;
  int q = lane >> 4, r = lane & 15;
  int wm = wid >> 1, wn = wid & 1;
  int node0 = blockIdx.x * 128;
  int srow  = tid >> 1;
  int skoff = (tid & 1) << 4;

  f32x4 acc[4][4];
  #pragma unroll
  for (int i = 0; i < 4; ++i)
    #pragma unroll
    for (int j = 0; j < 4; ++j) acc[i][j] = (f32x4)0.f;

  for (int k0 = 0; k0 < K; k0 += 32) {
    int gn = node0 + srow;
    float xv[16];
    if (gn < M) {
      const float* src = A + (size_t)gn * K + k0 + skoff;
      #pragma unroll
      for (int j = 0; j < 4; ++j) {
        float4 t = *(const float4*)(src + j * 4);
        xv[j * 4 + 0] = t.x; xv[j * 4 + 1] = t.y;
        xv[j * 4 + 2] = t.z; xv[j * 4 + 3] = t.w;
      }
    } else {
      #pragma unroll
      for (int j = 0; j < 16; ++j) xv[j] = 0.f;
    }
    const u16* wsrc = wth + (size_t)srow * K + k0 + skoff;
    const u16* lsrc = wtl + (size_t)srow * K + k0 + skoff;
    short8 wh0 = *(const short8*)wsrc;
    short8 wh1 = *(const short8*)(wsrc + 8);
    short8 wl0 = *(const short8*)lsrc;
    short8 wl1 = *(const short8*)(lsrc + 8);
    __syncthreads();
    short8 xh0, xh1, xl0, xl1;
    #pragma unroll
    for (int j = 0; j < 8; ++j) {
      u16 h, l;
      splitbf(xv[j], h, l);     xh0[j] = (short)h; xl0[j] = (short)l;
      splitbf(xv[j + 8], h, l); xh1[j] = (short)h; xl1[j] = (short)l;
    }
    *(short8*)&Xh[srow][skoff]     = xh0;
    *(short8*)&Xh[srow][skoff + 8] = xh1;
    *(short8*)&Xl[srow][skoff]     = xl0;
    *(short8*)&Xl[srow][skoff + 8] = xl1;
    *(short8*)&Gh[srow][skoff]     = wh0;
    *(short8*)&Gh[srow][skoff + 8] = wh1;
    *(short8*)&Gl[srow][skoff]     = wl0;
    *(short8*)&Gl[srow][skoff + 8] = wl1;
    __syncthreads();
    short8 ah[4], al[4], bh[4], bl[4];
    #pragma unroll
    for (int mi = 0; mi < 4; ++mi) {
      int row = wm * 64 + mi * 16 + r;
      ah[mi] = *(const short8*)&Gh[row][q * 8];
      al[mi] = *(const short8*)&Gl[row][q * 8];
    }
    #pragma unroll
    for (int ni = 0; ni < 4; ++ni) {
      int row = wn * 64 + ni * 16 + r;
      bh[ni] = *(const short8*)&Xh[row][q * 8];
      bl[ni] = *(const short8*)&Xl[row][q * 8];
    }
    #pragma unroll
    for (int mi = 0; mi < 4; ++mi)
      #pragma unroll
      for (int ni = 0; ni < 4; ++ni) {
        acc[mi][ni] = __builtin_amdgcn_mfma_f32_16x16x32_bf16(ah[mi], bh[ni], acc[mi][ni], 0, 0, 0);
        acc[mi][ni] = __builtin_amdgcn_mfma_f32_16x16x32_bf16(ah[mi], bl[ni], acc[mi][ni], 0, 0, 0);
        acc[mi][ni] = __builtin_amdgcn_mfma_f32_16x16x32_bf16(al[mi], bh[ni], acc[mi][ni], 0, 0, 0);
      }
  }
  #pragma unroll
  for (int ni = 0; ni < 4; ++ni) {
    int node = node0 + wn * 64 + ni * 16 + r;
    if (node < M) {
      #pragma unroll
      for (int mi = 0; mi < 4; ++mi) {
        int chb = wm * 64 + mi * 16 + q * 4;
        __half hh[4];
        hh[0] = __float2half(acc[mi][ni][0]);
        hh[1] = __float2half(acc[mi][ni][1]);
        hh[2] = __float2half(acc[mi][ni][2]);
        hh[3] = __float2half(acc[mi][ni][3]);
        *(float2*)(h16 + (size_t)node * HC + chb) = *(float2*)hh;
      }
    }
  }
}

// ---- per-node attention coefficients from fp16 h (one wave per node) ----
__global__ __launch_bounds__(256) void attn_coef16_kernel(const __half* __restrict__ h,
    const float* __restrict__ att_s, const float* __restrict__ att_d,
    float* __restrict__ a_s, float* __restrict__ a_d, int n) {
  int lane = threadIdx.x & 63, wid = threadIdx.x >> 6;
  int node = blockIdx.x * 4 + wid;
  if (node >= n) return;
  __half2 hv = *(const __half2*)(h + (size_t)node * HC + 2 * lane);
  float v0 = __low2float(hv), v1 = __high2float(hv);
  float2 as2 = *(const float2*)(att_s + 2 * lane);
  float2 ad2 = *(const float2*)(att_d + 2 * lane);
  float ps = v0 * as2.x + v1 * as2.y;
  float pd = v0 * ad2.x + v1 * ad2.y;
  #pragma unroll
  for (int o = 1; o < 16; o <<= 1) {
    ps += __shfl_xor(ps, o, 64);
    pd += __shfl_xor(pd, o, 64);
  }
  if ((lane & 15) == 0) {
    a_s[(size_t)node * 4 + (lane >> 4)] = ps;
    a_d[(size_t)node * 4 + (lane >> 4)] = pd;
  }
}

// ---------------- fused alpha + softmax + aggregation, one WAVE per node ----------------
__global__ __launch_bounds__(256) void aggregate_kernel(const __half* __restrict__ h,
    const int2* __restrict__ swp, const int* __restrict__ offs,
    const float* __restrict__ a_s, const float* __restrict__ a_d,
    const float* __restrict__ cptr, const float* __restrict__ bias,
    float* __restrict__ out, int n) {
  __shared__ float4 wals[4][TILE];
  __shared__ int    ssh[4][TILE];
  int lane = threadIdx.x & 63;
  int wv   = threadIdx.x >> 6;
  int v    = blockIdx.x * 4 + wv;
  if (v >= n) return;
  int r0  = offs[v];
  int deg = offs[v + 1] - r0;
  float4 c  = *(const float4*)cptr;
  float4 ad = *(const float4*)(a_d + (size_t)v * 4);
  int head  = lane >> 4;
  float2 acc = make_float2(0.f, 0.f);
  const __half* hb = h + 2 * lane;
  float4 mx = make_float4(-INFINITY, -INFINITY, -INFINITY, -INFINITY);
  float4 sm = make_float4(0.f, 0.f, 0.f, 0.f);

  if (deg <= TILE) {
    for (int i = lane; i < deg; i += 64) {
      int2 sw = swp[r0 + i];
      float w = __int_as_float(sw.y);
      float4 as = *(const float4*)(a_s + (size_t)sw.x * 4);
      float4 al = alpha4(as, ad, w, c);
      wals[wv][i] = al; ssh[wv][i] = sw.x;
      mx.x = fmaxf(mx.x, al.x); mx.y = fmaxf(mx.y, al.y);
      mx.z = fmaxf(mx.z, al.z); mx.w = fmaxf(mx.w, al.w);
    }
    wave_max4(mx);
    for (int i = lane; i < deg; i += 64) {
      float4 al = wals[wv][i];
      float4 e;
      e.x = expf(al.x - mx.x); e.y = expf(al.y - mx.y);
      e.z = expf(al.z - mx.z); e.w = expf(al.w - mx.w);
      wals[wv][i] = e;
      sm.x += e.x; sm.y += e.y; sm.z += e.z; sm.w += e.w;
    }
    wave_sum4(sm);
    int i = 0;
    for (; i + 8 <= deg; i += 8) {
      float wr[8]; int sr[8];
      #pragma unroll
      for (int j = 0; j < 8; ++j) {
        sr[j] = ssh[wv][i + j];
        wr[j] = ((const float*)&wals[wv][i + j])[head];
      }
      __half2 hv[8];
      #pragma unroll
      for (int j = 0; j < 8; ++j)
        hv[j] = *(const __half2*)(hb + (size_t)sr[j] * HC);
      #pragma unroll
      for (int j = 0; j < 8; ++j) {
        acc.x += wr[j] * __low2float(hv[j]);
        acc.y += wr[j] * __high2float(hv[j]);
      }
    }
    for (; i < deg; ++i) {
      int s0 = ssh[wv][i];
      float w0 = ((const float*)&wals[wv][i])[head];
      __half2 hvv = *(const __half2*)(hb + (size_t)s0 * HC);
      acc.x += w0 * __low2float(hvv);
      acc.y += w0 * __high2float(hvv);
    }
  } else {
    for (int i = lane; i < deg; i += 64) {
      int2 sw = swp[r0 + i];
      float4 as = *(const float4*)(a_s + (size_t)sw.x * 4);
      float4 al = alpha4(as, ad, __int_as_float(sw.y), c);
      mx.x = fmaxf(mx.x, al.x); mx.y = fmaxf(mx.y, al.y);
      mx.z = fmaxf(mx.z, al.z); mx.w = fmaxf(mx.w, al.w);
    }
    wave_max4(mx);
    for (int i = lane; i < deg; i += 64) {
      int2 sw = swp[r0 + i];
      float4 as = *(const float4*)(a_s + (size_t)sw.x * 4);
      float4 al = alpha4(as, ad, __int_as_float(sw.y), c);
      sm.x += expf(al.x - mx.x); sm.y += expf(al.y - mx.y);
      sm.z += expf(al.z - mx.z); sm.w += expf(al.w - mx.w);
    }
    wave_sum4(sm);
    float mxh = selh(mx, head);
    for (int i = 0; i < deg; ++i) {
      int2 sw = swp[r0 + i];
      float4 as = *(const float4*)(a_s + (size_t)sw.x * 4);
      float4 al = alpha4(as, ad, __int_as_float(sw.y), c);
      float e = expf(selh(al, head) - mxh);
      __half2 hvv = *(const __half2*)(hb + (size_t)sw.x * HC);
      acc.x += e * __low2float(hvv);
      acc.y += e * __high2float(hvv);
    }
  }
  float inv = 1.0f / selh(sm, head);
  float2 bb = *(const float2*)(bias + 2 * lane);
  float2 r;
  r.x = acc.x * inv + bb.x;
  r.y = acc.y * inv + bb.y;
  *(float2*)(out + (size_t)v * HC + 2 * lane) = r;
}

// ---------------- launcher ----------------
extern "C" void kernel_launch(void* const* d_in, const int* in_sizes, int n_in,
                              void* d_out, int out_size, void* d_ws, size_t ws_size,
                              hipStream_t stream) {
  const float* x   = (const float*)d_in[0];
  const void*  ei  = d_in[1];
  const float* ew  = (const float*)d_in[2];
  const float* W1  = (const float*)d_in[3];
  const float* as1 = (const float*)d_in[4];
  const float* ad1 = (const float*)d_in[5];
  const float* We1 = (const float*)d_in[6];
  const float* ae1 = (const float*)d_in[7];
  const float* b1  = (const float*)d_in[8];
  const float* W2  = (const float*)d_in[9];
  const float* as2 = (const float*)d_in[10];
  const float* ad2 = (const float*)d_in[11];
  const float* We2 = (const float*)d_in[12];
  const float* ae2 = (const float*)d_in[13];
  const float* b2  = (const float*)d_in[14];
  float* out = (float*)d_out;

  char* p = (char*)d_ws;
  auto alloc = [&](size_t b) { char* r = p; p += (b + 255) & ~(size_t)255; return r; };
  float*  scal     = (float*)alloc(256);
  __half* h16      = (__half*)alloc((size_t)N_NODES * HC * 2);
  float*  out1     = (float*)alloc((size_t)N_NODES * HC * 4);
  float*  a_s      = (float*)alloc((size_t)N_NODES * 4 * 4);
  float*  a_d      = (float*)alloc((size_t)N_NODES * 4 * 4);
  int*    offs     = (int*)alloc((size_t)(N_NODES + 1) * 4);
  int*    cnt      = (int*)alloc((size_t)NCH * NP * 4);
  int*    base_rel = (int*)alloc((size_t)NCH * NP * 4);
  int*    ptot     = (int*)alloc((size_t)NP * 4);
  int*    pofs     = (int*)alloc((size_t)(NP + 1) * 4);
  int2*   swp1     = (int2*)alloc((size_t)E_TOT * 8);
  int2*   swp2     = (int2*)alloc((size_t)E_TOT * 8);
  u16*    w1h      = (u16*)alloc((size_t)128 * 256 * 2);
  u16*    w1l      = (u16*)alloc((size_t)128 * 256 * 2);
  u16*    w2h      = (u16*)alloc((size_t)128 * 128 * 2);
  u16*    w2l      = (u16*)alloc((size_t)128 * 128 * 2);

  hipMemsetAsync(scal, 0, 256, stream);

  int* flag = (int*)scal + 16;

  detect_kernel<<<1, 64, 0, stream>>>(ei, flag);
  chunkhist_kernel<<<NCH, 256, 0, stream>>>(ei, flag, ew, cnt, scal);
  colscan_kernel<<<NP, 256, 0, stream>>>(cnt, base_rel, ptot);
  pscan_prep_kernel<<<1, 256, 0, stream>>>(ptot, pofs, We1, ae1, We2, ae2, scal,
                                           1.0f / N_EDGES);
  partition_kernel<<<NCH, 256, 0, stream>>>(ei, flag, ew, scal, base_rel, pofs, swp1);
  localsort_kernel<<<NP, 256, 0, stream>>>(swp1, pofs, offs, swp2);
  wprep_kernel<<<192, 256, 0, stream>>>(W1, W2, w1h, w1l, w2h, w2l);

  const int ggrid = (N_NODES + 127) / 128;
  const int agrid = (N_NODES + 3) / 4;
  // layer 1
  mfma_gemm_kernel<<<ggrid, 256, 0, stream>>>(x, w1h, w1l, h16, N_NODES, 256);
  attn_coef16_kernel<<<agrid, 256, 0, stream>>>(h16, as1, ad1, a_s, a_d, N_NODES);
  aggregate_kernel<<<agrid, 256, 0, stream>>>(h16, swp2, offs, a_s, a_d, scal + 4, b1,
                                              out1, N_NODES);
  // layer 2
  mfma_gemm_kernel<<<ggrid, 256, 0, stream>>>(out1, w2h, w2l, h16, N_NODES, 128);
  attn_coef16_kernel<<<agrid, 256, 0, stream>>>(h16, as2, ad2, a_s, a_d, N_NODES);
  aggregate_kernel<<<agrid, 256, 0, stream>>>(h16, swp2, offs, a_s, a_d, scal + 8, b2,
                                              out, N_NODES);
}

// Round 8
// 293.859 us; speedup vs baseline: 2.6948x; 1.0165x over previous
//
#include <hip/hip_runtime.h>
#include <hip/hip_fp16.h>

#define N_NODES 50000
#define N_EDGES 800000
#define E_TOT   850000   // N_EDGES + N_NODES self loops
#define HC 128
#define NEG_SLOPE 0.2f
#define TILE 128         // per-wave LDS edge tile (deg>TILE uses slow exact fallback)
#define KP 40            // MFMA LDS k-pitch (bf16 elems): 32 + 8 pad
#define CH 4096                              // edges per sort chunk
#define NCH ((E_TOT + CH - 1) / CH)          // 208 chunks  (< 256 required)
#define NP  ((N_NODES + 255) >> 8)           // 196 partitions of 256 dsts (< 256 required)

typedef unsigned short u16;
typedef __attribute__((ext_vector_type(8))) short short8;
typedef __attribute__((ext_vector_type(4))) float f32x4;

// ---------------- helpers ----------------
__device__ __forceinline__ int edge_get(const void* eidx, int f64, long long i) {
  return f64 ? (int)((const long long*)eidx)[i] : ((const int*)eidx)[i];
}
__device__ __forceinline__ float selh(float4 q, int head) {
  float a = (head & 1) ? q.y : q.x;
  float b = (head & 1) ? q.w : q.z;
  return (head & 2) ? b : a;
}
__device__ __forceinline__ float4 alpha4(float4 as, float4 ad, float w, float4 c) {
  float4 r;
  r.x = as.x + ad.x + w * c.x; r.x = r.x > 0.f ? r.x : NEG_SLOPE * r.x;
  r.y = as.y + ad.y + w * c.y; r.y = r.y > 0.f ? r.y : NEG_SLOPE * r.y;
  r.z = as.z + ad.z + w * c.z; r.z = r.z > 0.f ? r.z : NEG_SLOPE * r.z;
  r.w = as.w + ad.w + w * c.w; r.w = r.w > 0.f ? r.w : NEG_SLOPE * r.w;
  return r;
}
__device__ __forceinline__ void wave_max4(float4& m) {
  #pragma unroll
  for (int o = 1; o < 64; o <<= 1) {
    m.x = fmaxf(m.x, __shfl_xor(m.x, o, 64));
    m.y = fmaxf(m.y, __shfl_xor(m.y, o, 64));
    m.z = fmaxf(m.z, __shfl_xor(m.z, o, 64));
    m.w = fmaxf(m.w, __shfl_xor(m.w, o, 64));
  }
}
__device__ __forceinline__ void wave_sum4(float4& s) {
  #pragma unroll
  for (int o = 1; o < 64; o <<= 1) {
    s.x += __shfl_xor(s.x, o, 64);
    s.y += __shfl_xor(s.y, o, 64);
    s.z += __shfl_xor(s.z, o, 64);
    s.w += __shfl_xor(s.w, o, 64);
  }
}
__device__ __forceinline__ void splitbf(float v, u16& h, u16& l) {
  unsigned b = __float_as_uint(v);
  h = (u16)(b >> 16);
  float lo = v - __uint_as_float(b & 0xFFFF0000u);
  l = (u16)(__float_as_uint(lo) >> 16);
}
// 256-thread block exclusive scan (4 waves).
__device__ __forceinline__ int block_scan_excl(int val, int* lds) {
  int lane = threadIdx.x & 63, wv = threadIdx.x >> 6;
  int inc = val;
  #pragma unroll
  for (int off = 1; off < 64; off <<= 1) {
    int t = __shfl_up(inc, off, 64);
    if (lane >= off) inc += t;
  }
  if (lane == 63) lds[wv] = inc;
  __syncthreads();
  if (threadIdx.x == 0) {
    int s = 0;
    #pragma unroll
    for (int i = 0; i < 4; ++i) { int t = lds[i]; lds[i] = s; s += t; }
  }
  __syncthreads();
  return lds[wv] + inc - val;
}
// block-local int64/int32 probe (wave 0 ballot), result broadcast via LDS
__device__ __forceinline__ int local_detect(const void* eidx, int* f_sh) {
  int tid = threadIdx.x;
  if (tid < 64) {
    long long v = ((const long long*)eidx)[tid];
    int bad = (v < 0 || v >= N_NODES);
    unsigned long long anybad = __ballot(bad);
    if (tid == 0) *f_sh = (anybad == 0ull);
  }
  __syncthreads();
  return *f_sh;
}

// ---- CSR build, pass A: per-chunk partition histogram (LDS only) + ew sum ----
// scal layout (floats): [0]=sum(ew) [1]=mean [4..7]=c1 [8..11]=c2
__global__ __launch_bounds__(256) void chunkhist_kernel(const void* eidx,
    const float* __restrict__ ew, int* __restrict__ cnt, float* __restrict__ scal) {
  __shared__ int hist[NP];
  __shared__ float sh[4];
  __shared__ int f_sh;
  int c = blockIdx.x, tid = threadIdx.x;
  for (int i = tid; i < NP; i += 256) hist[i] = 0;
  int f = local_detect(eidx, &f_sh);   // includes a __syncthreads after hist init
  int i0 = c * CH, i1 = min(i0 + CH, E_TOT);
  float s = 0.f;
  for (int i = i0 + tid; i < i1; i += 256) {
    int d = (i < N_EDGES) ? edge_get(eidx, f, (long long)N_EDGES + i) : (i - N_EDGES);
    atomicAdd(&hist[d >> 8], 1);
    if (i < N_EDGES) s += ew[i];
  }
  #pragma unroll
  for (int m = 32; m >= 1; m >>= 1) s += __shfl_xor(s, m, 64);
  int lane = tid & 63, wv = tid >> 6;
  if (lane == 0) sh[wv] = s;
  __syncthreads();
  for (int i = tid; i < NP; i += 256) cnt[c * NP + i] = hist[i];
  if (tid == 0) atomicAdd(&scal[0], sh[0] + sh[1] + sh[2] + sh[3]);
}

// ---- pass B1: per-partition column scan over chunks ----
__global__ __launch_bounds__(256) void colscan_kernel(const int* __restrict__ cnt,
    int* __restrict__ base_rel, int* __restrict__ ptot) {
  __shared__ int lds[4];
  int p = blockIdx.x, c = threadIdx.x;
  int v = (c < NCH) ? cnt[c * NP + p] : 0;
  int e = block_scan_excl(v, lds);
  if (c < NCH) base_rel[c * NP + p] = e;
  if (c == 255) ptot[p] = e;
}

// ---- pass B2: scan partition totals -> pofs; fold in prep constants ----
__global__ __launch_bounds__(256) void pscan_prep_kernel(const int* __restrict__ ptot,
    int* __restrict__ pofs, const float* __restrict__ We1, const float* __restrict__ ae1,
    const float* __restrict__ We2, const float* __restrict__ ae2,
    float* __restrict__ scal, float inv_e) {
  __shared__ int lds[4];
  int t = threadIdx.x;
  int v = (t < NP) ? ptot[t] : 0;
  int e = block_scan_excl(v, lds);
  if (t <= NP) pofs[t] = e;
  float p = (t < 128) ? We1[t] * ae1[t] : We2[t - 128] * ae2[t - 128];
  #pragma unroll
  for (int m = 16; m >= 1; m >>= 1) p += __shfl_xor(p, m, 32);
  if ((t & 31) == 0) {
    int hd = (t & 127) >> 5;
    if (t < 128) scal[4 + hd] = p; else scal[8 + hd] = p;
  }
  if (t == 0) scal[1] = scal[0] * inv_e;
}

// ---- pass C: partition edges (block-exclusive contiguous runs per partition) ----
// record: x = (dst<<16)|src  (N_NODES<65536), y = bits(w)
__global__ __launch_bounds__(256) void partition_kernel(const void* eidx,
    const float* __restrict__ ew, const float* __restrict__ scal,
    const int* __restrict__ base_rel, const int* __restrict__ pofs,
    int2* __restrict__ swp1) {
  __shared__ int cur[NP];
  __shared__ int f_sh;
  int c = blockIdx.x, tid = threadIdx.x;
  for (int i = tid; i < NP; i += 256) cur[i] = base_rel[c * NP + i] + pofs[i];
  int f = local_detect(eidx, &f_sh);
  float wmean = scal[1];
  int i0 = c * CH, i1 = min(i0 + CH, E_TOT);
  for (int i = i0 + tid; i < i1; i += 256) {
    int s, d; float w;
    if (i < N_EDGES) {
      s = edge_get(eidx, f, i);
      d = edge_get(eidx, f, (long long)N_EDGES + i);
      w = ew[i];
    } else {
      s = d = i - N_EDGES;
      w = wmean;
    }
    int pos = atomicAdd(&cur[d >> 8], 1);
    swp1[pos] = make_int2((int)(((unsigned)d << 16) | (unsigned)s), __float_as_int(w));
  }
}

// ---- pass D: per-partition local counting sort (one block per partition) ----
__global__ __launch_bounds__(256) void localsort_kernel(const int2* __restrict__ swp1,
    const int* __restrict__ pofs, int* __restrict__ offs, int2* __restrict__ swp2) {
  __shared__ int lhist[256];
  __shared__ int lds[4];
  int p = blockIdx.x, tid = threadIdx.x;
  int r0 = pofs[p], r1 = pofs[p + 1];
  lhist[tid] = 0;
  __syncthreads();
  for (int i = r0 + tid; i < r1; i += 256) {
    unsigned key = (unsigned)swp1[i].x;
    atomicAdd(&lhist[(key >> 16) & 255u], 1);
  }
  __syncthreads();
  int v = lhist[tid];
  int e = block_scan_excl(v, lds);
  int node = (p << 8) + tid;
  if (node < N_NODES) offs[node] = r0 + e;
  if (p == 0 && tid == 0) offs[N_NODES] = E_TOT;
  lhist[tid] = e;
  __syncthreads();
  for (int i = r0 + tid; i < r1; i += 256) {
    int2 rec = swp1[i];
    unsigned key = (unsigned)rec.x;
    int pos = r0 + atomicAdd(&lhist[(key >> 16) & 255u], 1);
    swp2[pos] = make_int2((int)(key & 0xFFFFu), rec.y);
  }
}

// ---- pre-split W^T into bf16 hi/lo: wt[ch][k] = split(W[k][ch]) ----
__global__ __launch_bounds__(256) void wprep_kernel(const float* __restrict__ W1,
    const float* __restrict__ W2, u16* __restrict__ w1h, u16* __restrict__ w1l,
    u16* __restrict__ w2h, u16* __restrict__ w2l) {
  int i = blockIdx.x * 256 + threadIdx.x;
  if (i < 128 * 256) {
    int ch = i >> 8, k = i & 255;
    u16 h, l; splitbf(W1[k * 128 + ch], h, l);
    w1h[i] = h; w1l[i] = l;
  } else if (i < 128 * 256 + 128 * 128) {
    int j = i - 128 * 256;
    int ch = j >> 7, k = j & 127;
    u16 h, l; splitbf(W2[k * 128 + ch], h, l);
    w2h[j] = h; w2l[j] = l;
  }
}

// ---- split-bf16 MFMA GEMM + fused attention-coefficient epilogue ----
// h^T = W^T(128 x K) * x^T(K x M), h16[M x 128] fp16; a_s[r][hd], a_d[r][hd] from acc.
// C/D frag: col=lane&15 (node), row=(lane>>4)*4+reg (ch). ch = wm*64+mi*16+q*4+t,
// head = ch>>5 = wm*2 + (mi>>1). q-reduce via shfl_xor(16/32); wave (wm,wn) owns a
// disjoint (node-range, head-pair) -> direct float2 stores, no atomics.
__global__ __launch_bounds__(256) void mfma_gemm_kernel(const float* __restrict__ A,
    const u16* __restrict__ wth, const u16* __restrict__ wtl,
    const float* __restrict__ att_s, const float* __restrict__ att_d,
    __half* __restrict__ h16, float* __restrict__ a_s, float* __restrict__ a_d,
    int M, int K) {
  __shared__ u16 Xh[128][KP], Xl[128][KP];   // [node][k]
  __shared__ u16 Gh[128][KP], Gl[128][KP];   // [ch][k]  (W^T)
  int tid  = threadIdx.x;
  int lane = tid & 63, wid = tid >> 6;
  int q = lane >> 4, r = lane & 15;
  int wm = wid >> 1, wn = wid & 1;
  int node0 = blockIdx.x * 128;
  int srow  = tid >> 1;
  int skoff = (tid & 1) << 4;

  f32x4 acc[4][4];
  #pragma unroll
  for (int i = 0; i < 4; ++i)
    #pragma unroll
    for (int j = 0; j < 4; ++j) acc[i][j] = (f32x4)0.f;

  for (int k0 = 0; k0 < K; k0 += 32) {
    int gn = node0 + srow;
    float xv[16];
    if (gn < M) {
      const float* src = A + (size_t)gn * K + k0 + skoff;
      #pragma unroll
      for (int j = 0; j < 4; ++j) {
        float4 t = *(const float4*)(src + j * 4);
        xv[j * 4 + 0] = t.x; xv[j * 4 + 1] = t.y;
        xv[j * 4 + 2] = t.z; xv[j * 4 + 3] = t.w;
      }
    } else {
      #pragma unroll
      for (int j = 0; j < 16; ++j) xv[j] = 0.f;
    }
    const u16* wsrc = wth + (size_t)srow * K + k0 + skoff;
    const u16* lsrc = wtl + (size_t)srow * K + k0 + skoff;
    short8 wh0 = *(const short8*)wsrc;
    short8 wh1 = *(const short8*)(wsrc + 8);
    short8 wl0 = *(const short8*)lsrc;
    short8 wl1 = *(const short8*)(lsrc + 8);
    __syncthreads();
    short8 xh0, xh1, xl0, xl1;
    #pragma unroll
    for (int j = 0; j < 8; ++j) {
      u16 h, l;
      splitbf(xv[j], h, l);     xh0[j] = (short)h; xl0[j] = (short)l;
      splitbf(xv[j + 8], h, l); xh1[j] = (short)h; xl1[j] = (short)l;
    }
    *(short8*)&Xh[srow][skoff]     = xh0;
    *(short8*)&Xh[srow][skoff + 8] = xh1;
    *(short8*)&Xl[srow][skoff]     = xl0;
    *(short8*)&Xl[srow][skoff + 8] = xl1;
    *(short8*)&Gh[srow][skoff]     = wh0;
    *(short8*)&Gh[srow][skoff + 8] = wh1;
    *(short8*)&Gl[srow][skoff]     = wl0;
    *(short8*)&Gl[srow][skoff + 8] = wl1;
    __syncthreads();
    short8 ah[4], al[4], bh[4], bl[4];
    #pragma unroll
    for (int mi = 0; mi < 4; ++mi) {
      int row = wm * 64 + mi * 16 + r;
      ah[mi] = *(const short8*)&Gh[row][q * 8];
      al[mi] = *(const short8*)&Gl[row][q * 8];
    }
    #pragma unroll
    for (int ni = 0; ni < 4; ++ni) {
      int row = wn * 64 + ni * 16 + r;
      bh[ni] = *(const short8*)&Xh[row][q * 8];
      bl[ni] = *(const short8*)&Xl[row][q * 8];
    }
    #pragma unroll
    for (int mi = 0; mi < 4; ++mi)
      #pragma unroll
      for (int ni = 0; ni < 4; ++ni) {
        acc[mi][ni] = __builtin_amdgcn_mfma_f32_16x16x32_bf16(ah[mi], bh[ni], acc[mi][ni], 0, 0, 0);
        acc[mi][ni] = __builtin_amdgcn_mfma_f32_16x16x32_bf16(ah[mi], bl[ni], acc[mi][ni], 0, 0, 0);
        acc[mi][ni] = __builtin_amdgcn_mfma_f32_16x16x32_bf16(al[mi], bh[ni], acc[mi][ni], 0, 0, 0);
      }
  }
  // att vectors for my 16 chs: ch = wm*64 + mi*16 + q*4 + t
  float4 sv[4], dv[4];
  #pragma unroll
  for (int mi = 0; mi < 4; ++mi) {
    sv[mi] = *(const float4*)(att_s + wm * 64 + mi * 16 + q * 4);
    dv[mi] = *(const float4*)(att_d + wm * 64 + mi * 16 + q * 4);
  }
  #pragma unroll
  for (int ni = 0; ni < 4; ++ni) {
    int node = node0 + wn * 64 + ni * 16 + r;
    // h16 store
    if (node < M) {
      #pragma unroll
      for (int mi = 0; mi < 4; ++mi) {
        int chb = wm * 64 + mi * 16 + q * 4;
        __half hh[4];
        hh[0] = __float2half(acc[mi][ni][0]);
        hh[1] = __float2half(acc[mi][ni][1]);
        hh[2] = __float2half(acc[mi][ni][2]);
        hh[3] = __float2half(acc[mi][ni][3]);
        *(float2*)(h16 + (size_t)node * HC + chb) = *(float2*)hh;
      }
    }
    // fused a_s/a_d: head pair (wm*2, wm*2+1) <- mi pairs (0,1) and (2,3)
    float ps0 = 0.f, pd0 = 0.f, ps1 = 0.f, pd1 = 0.f;
    #pragma unroll
    for (int mi = 0; mi < 2; ++mi)
      #pragma unroll
      for (int t = 0; t < 4; ++t) {
        float av = acc[mi][ni][t];
        ps0 += av * ((const float*)&sv[mi])[t];
        pd0 += av * ((const float*)&dv[mi])[t];
      }
    #pragma unroll
    for (int mi = 2; mi < 4; ++mi)
      #pragma unroll
      for (int t = 0; t < 4; ++t) {
        float av = acc[mi][ni][t];
        ps1 += av * ((const float*)&sv[mi])[t];
        pd1 += av * ((const float*)&dv[mi])[t];
      }
    ps0 += __shfl_xor(ps0, 16, 64); ps0 += __shfl_xor(ps0, 32, 64);
    pd0 += __shfl_xor(pd0, 16, 64); pd0 += __shfl_xor(pd0, 32, 64);
    ps1 += __shfl_xor(ps1, 16, 64); ps1 += __shfl_xor(ps1, 32, 64);
    pd1 += __shfl_xor(pd1, 16, 64); pd1 += __shfl_xor(pd1, 32, 64);
    if (q == 0 && node < M) {
      *(float2*)(a_s + (size_t)node * 4 + wm * 2) = make_float2(ps0, ps1);
      *(float2*)(a_d + (size_t)node * 4 + wm * 2) = make_float2(pd0, pd1);
    }
  }
}

// ---------------- fused alpha + softmax + aggregation, one WAVE per node ----------------
// Each lane owns output dims (2*lane, 2*lane+1); head = lane>>4. h gathered as fp16.
// Gather loop: uniform masked batch-16 (pads clamp to a repeated index, weight 0).
__global__ __launch_bounds__(256) void aggregate_kernel(const __half* __restrict__ h,
    const int2* __restrict__ swp, const int* __restrict__ offs,
    const float* __restrict__ a_s, const float* __restrict__ a_d,
    const float* __restrict__ cptr, const float* __restrict__ bias,
    float* __restrict__ out, int n) {
  __shared__ float4 wals[4][TILE];
  __shared__ int    ssh[4][TILE];
  int lane = threadIdx.x & 63;
  int wv   = threadIdx.x >> 6;
  int v    = blockIdx.x * 4 + wv;
  if (v >= n) return;
  int r0  = offs[v];
  int deg = offs[v + 1] - r0;
  float4 c  = *(const float4*)cptr;
  float4 ad = *(const float4*)(a_d + (size_t)v * 4);
  int head  = lane >> 4;
  float2 acc = make_float2(0.f, 0.f);
  const __half* hb = h + 2 * lane;
  float4 mx = make_float4(-INFINITY, -INFINITY, -INFINITY, -INFINITY);
  float4 sm = make_float4(0.f, 0.f, 0.f, 0.f);

  if (deg <= TILE) {
    for (int i = lane; i < deg; i += 64) {
      int2 sw = swp[r0 + i];
      float w = __int_as_float(sw.y);
      float4 as = *(const float4*)(a_s + (size_t)sw.x * 4);
      float4 al = alpha4(as, ad, w, c);
      wals[wv][i] = al; ssh[wv][i] = sw.x;
      mx.x = fmaxf(mx.x, al.x); mx.y = fmaxf(mx.y, al.y);
      mx.z = fmaxf(mx.z, al.z); mx.w = fmaxf(mx.w, al.w);
    }
    wave_max4(mx);
    for (int i = lane; i < deg; i += 64) {
      float4 al = wals[wv][i];
      float4 e;
      e.x = expf(al.x - mx.x); e.y = expf(al.y - mx.y);
      e.z = expf(al.z - mx.z); e.w = expf(al.w - mx.w);
      wals[wv][i] = e;
      sm.x += e.x; sm.y += e.y; sm.z += e.z; sm.w += e.w;
    }
    wave_sum4(sm);
    for (int i = 0; i < deg; i += 16) {
      float wr[16]; int sr[16];
      #pragma unroll
      for (int j = 0; j < 16; ++j) {
        int idx = i + j;
        bool ok = idx < deg;
        int ii = ok ? idx : i;
        sr[j] = ssh[wv][ii];
        wr[j] = ok ? ((const float*)&wals[wv][ii])[head] : 0.f;
      }
      __half2 hv[16];
      #pragma unroll
      for (int j = 0; j < 16; ++j)
        hv[j] = *(const __half2*)(hb + (size_t)sr[j] * HC);
      #pragma unroll
      for (int j = 0; j < 16; ++j) {
        acc.x += wr[j] * __low2float(hv[j]);
        acc.y += wr[j] * __high2float(hv[j]);
      }
    }
  } else {
    // exact streaming fallback (deg > TILE)
    for (int i = lane; i < deg; i += 64) {
      int2 sw = swp[r0 + i];
      float4 as = *(const float4*)(a_s + (size_t)sw.x * 4);
      float4 al = alpha4(as, ad, __int_as_float(sw.y), c);
      mx.x = fmaxf(mx.x, al.x); mx.y = fmaxf(mx.y, al.y);
      mx.z = fmaxf(mx.z, al.z); mx.w = fmaxf(mx.w, al.w);
    }
    wave_max4(mx);
    for (int i = lane; i < deg; i += 64) {
      int2 sw = swp[r0 + i];
      float4 as = *(const float4*)(a_s + (size_t)sw.x * 4);
      float4 al = alpha4(as, ad, __int_as_float(sw.y), c);
      sm.x += expf(al.x - mx.x); sm.y += expf(al.y - mx.y);
      sm.z += expf(al.z - mx.z); sm.w += expf(al.w - mx.w);
    }
    wave_sum4(sm);
    float mxh = selh(mx, head);
    for (int i = 0; i < deg; ++i) {
      int2 sw = swp[r0 + i];
      float4 as = *(const float4*)(a_s + (size_t)sw.x * 4);
      float4 al = alpha4(as, ad, __int_as_float(sw.y), c);
      float e = expf(selh(al, head) - mxh);
      __half2 hvv = *(const __half2*)(hb + (size_t)sw.x * HC);
      acc.x += e * __low2float(hvv);
      acc.y += e * __high2float(hvv);
    }
  }
  float inv = 1.0f / selh(sm, head);
  float2 bb = *(const float2*)(bias + 2 * lane);
  float2 r;
  r.x = acc.x * inv + bb.x;
  r.y = acc.y * inv + bb.y;
  *(float2*)(out + (size_t)v * HC + 2 * lane) = r;
}

// ---------------- launcher ----------------
extern "C" void kernel_launch(void* const* d_in, const int* in_sizes, int n_in,
                              void* d_out, int out_size, void* d_ws, size_t ws_size,
                              hipStream_t stream) {
  const float* x   = (const float*)d_in[0];
  const void*  ei  = d_in[1];
  const float* ew  = (const float*)d_in[2];
  const float* W1  = (const float*)d_in[3];
  const float* as1 = (const float*)d_in[4];
  const float* ad1 = (const float*)d_in[5];
  const float* We1 = (const float*)d_in[6];
  const float* ae1 = (const float*)d_in[7];
  const float* b1  = (const float*)d_in[8];
  const float* W2  = (const float*)d_in[9];
  const float* as2 = (const float*)d_in[10];
  const float* ad2 = (const float*)d_in[11];
  const float* We2 = (const float*)d_in[12];
  const float* ae2 = (const float*)d_in[13];
  const float* b2  = (const float*)d_in[14];
  float* out = (float*)d_out;

  char* p = (char*)d_ws;
  auto alloc = [&](size_t b) { char* r = p; p += (b + 255) & ~(size_t)255; return r; };
  float*  scal     = (float*)alloc(256);
  __half* h16      = (__half*)alloc((size_t)N_NODES * HC * 2);
  float*  out1     = (float*)alloc((size_t)N_NODES * HC * 4);
  float*  a_s      = (float*)alloc((size_t)N_NODES * 4 * 4);
  float*  a_d      = (float*)alloc((size_t)N_NODES * 4 * 4);
  int*    offs     = (int*)alloc((size_t)(N_NODES + 1) * 4);
  int*    cnt      = (int*)alloc((size_t)NCH * NP * 4);
  int*    base_rel = (int*)alloc((size_t)NCH * NP * 4);
  int*    ptot     = (int*)alloc((size_t)NP * 4);
  int*    pofs     = (int*)alloc((size_t)(NP + 1) * 4);
  int2*   swp1     = (int2*)alloc((size_t)E_TOT * 8);
  int2*   swp2     = (int2*)alloc((size_t)E_TOT * 8);
  u16*    w1h      = (u16*)alloc((size_t)128 * 256 * 2);
  u16*    w1l      = (u16*)alloc((size_t)128 * 256 * 2);
  u16*    w2h      = (u16*)alloc((size_t)128 * 128 * 2);
  u16*    w2l      = (u16*)alloc((size_t)128 * 128 * 2);

  hipMemsetAsync(scal, 0, 256, stream);

  chunkhist_kernel<<<NCH, 256, 0, stream>>>(ei, ew, cnt, scal);
  colscan_kernel<<<NP, 256, 0, stream>>>(cnt, base_rel, ptot);
  pscan_prep_kernel<<<1, 256, 0, stream>>>(ptot, pofs, We1, ae1, We2, ae2, scal,
                                           1.0f / N_EDGES);
  partition_kernel<<<NCH, 256, 0, stream>>>(ei, ew, scal, base_rel, pofs, swp1);
  localsort_kernel<<<NP, 256, 0, stream>>>(swp1, pofs, offs, swp2);
  wprep_kernel<<<192, 256, 0, stream>>>(W1, W2, w1h, w1l, w2h, w2l);

  const int ggrid = (N_NODES + 127) / 128;
  const int agrid = (N_NODES + 3) / 4;
  // layer 1
  mfma_gemm_kernel<<<ggrid, 256, 0, stream>>>(x, w1h, w1l, as1, ad1, h16, a_s, a_d,
                                              N_NODES, 256);
  aggregate_kernel<<<agrid, 256, 0, stream>>>(h16, swp2, offs, a_s, a_d, scal + 4, b1,
                                              out1, N_NODES);
  // layer 2
  mfma_gemm_kernel<<<ggrid, 256, 0, stream>>>(out1, w2h, w2l, as2, ad2, h16, a_s, a_d,
                                              N_NODES, 128);
  aggregate_kernel<<<agrid, 256, 0, stream>>>(h16, swp2, offs, a_s, a_d, scal + 8, b2,
                                              out, N_NODES);
}